// Round 5
// baseline (333.716 us; speedup 1.0000x reference)
//
#include <hip/hip_runtime.h>

// Shapes fixed by setup_inputs(): B=4, L=1024, E=1024, H=16, D=64, W=128
#define BB 4
#define LL 1024
#define EE 1024
#define HH 16
#define DD 64

typedef __attribute__((ext_vector_type(8))) short short8;
typedef __attribute__((ext_vector_type(4))) float floatx4;

#define PSTR ((size_t)4096 * 1024)   // split-K partial stride (elements, bf16)

__device__ __forceinline__ float bf2f(short s) {
    union { unsigned u; float f; } c;
    c.u = ((unsigned)(unsigned short)s) << 16;
    return c.f;
}
__device__ __forceinline__ short f2bf(float f) {
    union { float f; unsigned u; } c; c.f = f;
    unsigned r = c.u + 0x7fffu + ((c.u >> 16) & 1u);
    return (short)(r >> 16);
}

__device__ __forceinline__ void async_copy16(const void* g, void* l) {
    __builtin_amdgcn_global_load_lds(
        (const __attribute__((address_space(1))) unsigned int*)g,
        (__attribute__((address_space(3))) unsigned int*)l, 16, 0, 0);
}

// ---------------------------------------------------------------- convert (all 5 tensors, one launch)
__global__ __launch_bounds__(256) void cvt5(
    const float* __restrict__ x, const float* __restrict__ wqkv,
    const float* __restrict__ wo, const float* __restrict__ w1,
    const float* __restrict__ w2,
    short* __restrict__ xb, short* __restrict__ wqkvb, short* __restrict__ wob,
    short* __restrict__ w1b, short* __restrict__ w2b)
{
    int bi = blockIdx.x;
    const float* in; short* out; int base;
    if      (bi <  4096) { in = x;    out = xb;    base = 0;     }
    else if (bi <  7168) { in = wqkv; out = wqkvb; base = 4096;  }
    else if (bi <  8192) { in = wo;   out = wob;   base = 7168;  }
    else if (bi < 12288) { in = w1;   out = w1b;   base = 8192;  }
    else                 { in = w2;   out = w2b;   base = 12288; }
    int i = (bi - base) * 256 + threadIdx.x;
    float4 v = ((const float4*)in)[i];
    unsigned long long u =
          (unsigned long long)(unsigned short)f2bf(v.x)
        | ((unsigned long long)(unsigned short)f2bf(v.y) << 16)
        | ((unsigned long long)(unsigned short)f2bf(v.z) << 32)
        | ((unsigned long long)(unsigned short)f2bf(v.w) << 48);
    ((unsigned long long*)out)[i] = u;
}

// ---------------------------------------------------------------- GEMM 256x256 (NT), ring + phase pairs
// C[m,n] = sum_k A[m,k]*B[n,k] (+bias). BM=BN=256, BK=32, 512 thr / 8 waves (2Mx4N).
// LDS: 4-buffer ring, each A 256x32 + B 256x32 bf16 = 32 KiB (128 KiB total).
// Chunk swizzle: 16B chunk c of row r stored at position c ^ ((r>>1)&3) -> 2-way (free).
// Depth: tile t+3 staged during tile t; counted vmcnt(8) publishes t+1 (issued
// 3 tiles ~ >2000 cyc ago -> zero expected stall; younger loads NEVER drained).
// Phase structure (m201 ordering: reads BEFORE barrier, lgkm0 AFTER):
//   Phase A: {8 ds_read (af0-3,bf0-3), stageA(t+3), barrier, lgkm0, setprio1,
//             16 MFMA (m0-3 x n0-3), setprio0, barrier}
//   Phase B: {4 ds_read (af4-7), stageB(t+3), vmcnt(publish t+1), barrier, lgkm0,
//             setprio1, 16 MFMA (m4-7 x n0-3), setprio0, barrier}
// Read drain overlaps barrier wait; next phase's LDS reads run while MFMA pipe
// drains previous cluster (issue is non-blocking). Ledger: buf t published by
// phase-B(t-1) vmcnt+barrier; stage(t+3) overwrites buf (t-1)&3 whose reads were
// lgkm-drained before every wave's phase-B(t-1) barrier arrival.
template<bool RELU, bool SK>
__global__ __launch_bounds__(512, 2) void gemm256(
    const short* __restrict__ A, const short* __restrict__ Bw,
    const float* __restrict__ bias,
    short* __restrict__ Cb,
    int M, int N, int K, int Ksp)
{
    __shared__ short SH[67584];   // union{ 4-ring bufs 131072 B ; C stage 256x264x2 B }
    const int tid  = threadIdx.x;
    const int w    = tid >> 6, lane = tid & 63;
    const int fr   = lane & 15, quad = lane >> 4;
    const int wm   = w >> 2,  wn   = w & 3;

    // XCD-bijective block swizzle (all grids have nwg % 8 == 0)
    const int gx   = gridDim.x;                 // = M-tiles
    const int flat = blockIdx.y * gx + blockIdx.x;
    const int nwg  = gx * gridDim.y;
    const int q8   = nwg >> 3;
    const int swz  = (flat & 7) * q8 + (flat >> 3);
    const int m0   = (swz % gx) * 256;
    const int n0   = (swz / gx) * 256;

    const int kb = SK ? blockIdx.z * Ksp : 0;
    const int NT = (SK ? Ksp : K) >> 5;

    // staging: per tensor per tile each thread issues 2x16B (256x32 = 16 KiB).
    auto stageA = [&](int s) {
        if (s >= NT) return;
#pragma unroll
        for (int l = 0; l < 2; ++l) {
            int r = l * 128 + (tid >> 2);
            int g = (tid & 3) ^ ((r >> 1) & 3);
            async_copy16(A + (size_t)(m0 + r) * K + kb + s * 32 + g * 8,
                         SH + (s & 3) * 16384 + l * 4096 + w * 512);
        }
    };
    auto stageB = [&](int s) {
        if (s >= NT) return;
#pragma unroll
        for (int l = 0; l < 2; ++l) {
            int r = l * 128 + (tid >> 2);
            int g = (tid & 3) ^ ((r >> 1) & 3);
            async_copy16(Bw + (size_t)(n0 + r) * K + kb + s * 32 + g * 8,
                         SH + (s & 3) * 16384 + 8192 + l * 4096 + w * 512);
        }
    };

    floatx4 acc[8][4];
#pragma unroll
    for (int i = 0; i < 8; ++i)
#pragma unroll
        for (int j = 0; j < 4; ++j) acc[i][j] = (floatx4){0.f, 0.f, 0.f, 0.f};

    // prologue: stage tiles 0,1,2 (12 wave-instr in flight); publish tile 0
    stageA(0); stageB(0); stageA(1); stageB(1); stageA(2); stageB(2);
    asm volatile("s_waitcnt vmcnt(8)" ::: "memory");
    __builtin_amdgcn_sched_barrier(0);
    __builtin_amdgcn_s_barrier();

    const int pos = (quad ^ ((fr >> 1) & 3)) * 8;   // chunk position for frag reads

    for (int t = 0; t < NT; ++t) {
        const short* sA = SH + (t & 3) * 16384;
        const short* sB = sA + 8192;
        short8 af[8], bf[4];

        // ===== Phase A: reads g0 ; stageA(t+3) ; barrier ; lgkm0 ; MFMA g0 ; barrier
#pragma unroll
        for (int i = 0; i < 4; ++i) af[i] = *(const short8*)&sA[(wm * 128 + i * 16 + fr) * 32 + pos];
#pragma unroll
        for (int j = 0; j < 4; ++j) bf[j] = *(const short8*)&sB[(wn * 64 + j * 16 + fr) * 32 + pos];
        stageA(t + 3);
        __builtin_amdgcn_s_barrier();
        asm volatile("s_waitcnt lgkmcnt(0)" ::: "memory");
        __builtin_amdgcn_sched_barrier(0);
        __builtin_amdgcn_s_setprio(1);
#pragma unroll
        for (int i = 0; i < 4; ++i)
#pragma unroll
            for (int j = 0; j < 4; ++j)
                acc[i][j] = __builtin_amdgcn_mfma_f32_16x16x32_bf16(af[i], bf[j], acc[i][j], 0, 0, 0);
        __builtin_amdgcn_s_setprio(0);
        __builtin_amdgcn_sched_barrier(0);
        __builtin_amdgcn_s_barrier();

        // ===== Phase B: reads g1 ; stageB(t+3) ; vmcnt(publish t+1) ; barrier ; lgkm0 ; MFMA g1 ; barrier
#pragma unroll
        for (int i = 0; i < 4; ++i) af[i + 4] = *(const short8*)&sA[(wm * 128 + (i + 4) * 16 + fr) * 32 + pos];
        stageB(t + 3);
        {
            int rem = NT - 1 - t;   // tiles after t
            if (rem >= 3)      asm volatile("s_waitcnt vmcnt(8)" ::: "memory");
            else if (rem == 2) asm volatile("s_waitcnt vmcnt(4)" ::: "memory");
            else if (rem == 1) asm volatile("s_waitcnt vmcnt(0)" ::: "memory");
        }
        __builtin_amdgcn_sched_barrier(0);
        __builtin_amdgcn_s_barrier();
        asm volatile("s_waitcnt lgkmcnt(0)" ::: "memory");
        __builtin_amdgcn_sched_barrier(0);
        __builtin_amdgcn_s_setprio(1);
#pragma unroll
        for (int i = 0; i < 4; ++i)
#pragma unroll
            for (int j = 0; j < 4; ++j)
                acc[i + 4][j] = __builtin_amdgcn_mfma_f32_16x16x32_bf16(af[i + 4], bf[j], acc[i + 4][j], 0, 0, 0);
        __builtin_amdgcn_s_setprio(0);
        __builtin_amdgcn_sched_barrier(0);
        __builtin_amdgcn_s_barrier();
    }

    __syncthreads();   // ring drained; LDS reused for C staging

    // ---- epilogue: acc -> LDS bf16 [256][264] -> coalesced short8 global rows
    const int cc = lane & 15, rb4 = quad * 4;
#pragma unroll
    for (int i = 0; i < 8; ++i) {
        int row = wm * 128 + i * 16 + rb4;
#pragma unroll
        for (int j = 0; j < 4; ++j) {
            int col = wn * 64 + j * 16 + cc;
            float bv = SK ? 0.0f : bias[n0 + col];
#pragma unroll
            for (int r = 0; r < 4; ++r) {
                float v = acc[i][j][r] + bv;
                if (RELU) v = fmaxf(v, 0.0f);
                SH[(row + r) * 264 + col] = f2bf(v);
            }
        }
    }
    __syncthreads();
    short* Co = Cb + (SK ? (size_t)blockIdx.z * PSTR : 0);
#pragma unroll
    for (int it = 0; it < 16; ++it) {
        int idx = it * 512 + tid;
        int row = idx >> 5, ch = idx & 31;
        short8 v = *(const short8*)&SH[row * 264 + ch * 8];
        *(short8*)&Co[(size_t)(m0 + row) * N + n0 + ch * 8] = v;
    }
}

// ---------------------------------------------------------------- V transpose
// vt[((b*16+h)*64+d)*1024 + tok] = qkv[(b*1024+tok)*3072 + 2048 + h*64 + d]
__global__ __launch_bounds__(256) void vtrans(const short* __restrict__ qkv,
                                              short* __restrict__ vt)
{
    int id = blockIdx.x;                 // 1024 = 4b * 16h * 16 tok-blocks
    int tb = id & 15, h = (id >> 4) & 15, b = id >> 8;
    __shared__ short T[64 * 72];
    const short* src = qkv + (size_t)(b * 1024 + tb * 64) * 3072 + 2048 + h * 64;
    int tok = threadIdx.x >> 2;
    int c8  = threadIdx.x & 3;
#pragma unroll
    for (int q = 0; q < 2; ++q) {
        int d0 = (c8 * 2 + q) * 8;
        short8 v = *(const short8*)&src[(size_t)tok * 3072 + d0];
#pragma unroll
        for (int e = 0; e < 8; ++e) T[(d0 + e) * 72 + tok] = v[e];
    }
    __syncthreads();
    short* dst = vt + (size_t)((b * 16 + h) * 64) * 1024 + tb * 64;
    int d = threadIdx.x >> 2, cq = threadIdx.x & 3;
#pragma unroll
    for (int q = 0; q < 2; ++q) {
        int t0 = (cq * 2 + q) * 8;
        *(short8*)&dst[(size_t)d * 1024 + t0] = *(const short8*)&T[d * 72 + t0];
    }
}

// ---------------------------------------------------------------- GEMM (NT) 128x128 (out-proj)
template<bool RELU, bool SK>
__global__ __launch_bounds__(256) void gemm_bt(
    const short* __restrict__ A, const short* __restrict__ Bw,
    const float* __restrict__ bias,
    short* __restrict__ Cb,
    int M, int N, int K, int Ksp)
{
    __shared__ union U {
        struct { short As[128 * 64]; short Bs[128 * 64]; } s;
        short Cs[128 * 136];
    } u;
    const int tid  = threadIdx.x;
    const int wave = tid >> 6, lane = tid & 63;
    const int m0 = blockIdx.x * 128, n0 = blockIdx.y * 128;
    const int wm = (wave & 1) * 64, wn = (wave >> 1) * 64;
    const int kbase = SK ? blockIdx.z * Ksp : 0;

    floatx4 acc[4][4];
#pragma unroll
    for (int i = 0; i < 4; ++i)
#pragma unroll
        for (int j = 0; j < 4; ++j) acc[i][j] = (floatx4){0.f, 0.f, 0.f, 0.f};

    const int srow = wave * 8 + (lane >> 3);
    const int scol = (((lane & 7) ^ ((lane >> 3) & 7))) * 8;
    const short* gA = A  + (size_t)(m0 + srow) * K + kbase + scol;
    const short* gB = Bw + (size_t)(n0 + srow) * K + kbase + scol;
    short* lA = u.s.As + wave * 512;
    short* lB = u.s.Bs + wave * 512;

    const int fr = lane & 15, quad = lane >> 4;
    const int kiters = (SK ? Ksp : K) >> 6;
    for (int kt = 0; kt < kiters; ++kt) {
#pragma unroll
        for (int s = 0; s < 4; ++s) {
            async_copy16(gA + (size_t)s * 32 * K, lA + s * 2048);
            async_copy16(gB + (size_t)s * 32 * K, lB + s * 2048);
        }
        gA += 64; gB += 64;
        __syncthreads();
#pragma unroll
        for (int ks = 0; ks < 2; ++ks) {
            short8 af[4], bf[4];
#pragma unroll
            for (int i = 0; i < 4; ++i) {
                int pos = ((ks * 4 + quad) ^ (fr & 7)) * 8;
                af[i] = *(const short8*)&u.s.As[(wm + i * 16 + fr) * 64 + pos];
                bf[i] = *(const short8*)&u.s.Bs[(wn + i * 16 + fr) * 64 + pos];
            }
#pragma unroll
            for (int i = 0; i < 4; ++i)
#pragma unroll
                for (int j = 0; j < 4; ++j)
                    acc[i][j] = __builtin_amdgcn_mfma_f32_16x16x32_bf16(af[i], bf[j], acc[i][j], 0, 0, 0);
        }
        __syncthreads();
    }

    const int cc = lane & 15;
    const int rb = (lane >> 4) * 4;
#pragma unroll
    for (int j = 0; j < 4; ++j) {
        int col = wn + j * 16 + cc;
        float bv = SK ? 0.0f : bias[n0 + col];
#pragma unroll
        for (int i = 0; i < 4; ++i) {
            int row = wm + i * 16 + rb;
#pragma unroll
            for (int r = 0; r < 4; ++r) {
                float v = acc[i][j][r] + bv;
                if (RELU) v = fmaxf(v, 0.0f);
                u.Cs[(row + r) * 136 + col] = f2bf(v);
            }
        }
    }
    __syncthreads();
    short* Co = Cb + (SK ? (size_t)blockIdx.z * PSTR : 0);
    const int trow = tid >> 4, tcol = (tid & 15) * 8;
#pragma unroll
    for (int p = 0; p < 8; ++p) {
        int row = p * 16 + trow;
        short8 vv = *(const short8*)&u.Cs[row * 136 + tcol];
        *(short8*)&Co[(size_t)(m0 + row) * N + n0 + tcol] = vv;
    }
}

// ---------------------------------------------------------------- LayerNorm
__global__ __launch_bounds__(256) void ln_kernel(
    const float* __restrict__ xa, const short* __restrict__ parts, int nparts,
    const float* __restrict__ bias,
    const float* __restrict__ g, const float* __restrict__ beta,
    float* __restrict__ outf, short* __restrict__ outb)
{
    const int row = blockIdx.x;
    const int tid = threadIdx.x;
    float4 va = ((const float4*)(xa + (size_t)row * EE))[tid];
    float4 vb = ((const float4*)bias)[tid];
    float v0 = va.x + vb.x, v1 = va.y + vb.y, v2 = va.z + vb.z, v3 = va.w + vb.w;
#pragma unroll 4
    for (int p = 0; p < nparts; ++p) {
        unsigned long long u8 = ((const unsigned long long*)(parts + p * PSTR + (size_t)row * EE))[tid];
        v0 += bf2f((short)(u8 & 0xffff));
        v1 += bf2f((short)((u8 >> 16) & 0xffff));
        v2 += bf2f((short)((u8 >> 32) & 0xffff));
        v3 += bf2f((short)(u8 >> 48));
    }
    float s  = v0 + v1 + v2 + v3;
    float ss = v0 * v0 + v1 * v1 + v2 * v2 + v3 * v3;
#pragma unroll
    for (int o = 1; o < 64; o <<= 1) { s += __shfl_xor(s, o); ss += __shfl_xor(ss, o); }
    __shared__ float red[8];
    if ((tid & 63) == 0) { red[(tid >> 6) * 2] = s; red[(tid >> 6) * 2 + 1] = ss; }
    __syncthreads();
    s  = red[0] + red[2] + red[4] + red[6];
    ss = red[1] + red[3] + red[5] + red[7];
    float mean = s * (1.0f / EE);
    float var  = ss * (1.0f / EE) - mean * mean;
    float rstd = rsqrtf(var + 1e-5f);
    float4 vg = ((const float4*)g)[tid];
    float4 vt = ((const float4*)beta)[tid];
    float o0 = (v0 - mean) * rstd * vg.x + vt.x;
    float o1 = (v1 - mean) * rstd * vg.y + vt.y;
    float o2 = (v2 - mean) * rstd * vg.z + vt.z;
    float o3 = (v3 - mean) * rstd * vg.w + vt.w;
    if (outf) ((float4*)(outf + (size_t)row * EE))[tid] = make_float4(o0, o1, o2, o3);
    if (outb) {
        unsigned long long u =
              (unsigned long long)(unsigned short)f2bf(o0)
            | ((unsigned long long)(unsigned short)f2bf(o1) << 16)
            | ((unsigned long long)(unsigned short)f2bf(o2) << 32)
            | ((unsigned long long)(unsigned short)f2bf(o3) << 48);
        ((unsigned long long*)(outb + (size_t)row * EE))[tid] = u;
    }
}

// ---------------------------------------------------------------- attention (MFMA, register softmax)
// 64-row i-tile per block (same 320-col K window serves all 64 rows since 64+2*128=320).
// Grid 1024 = 16 i-tiles x 4b x 16h (i0 slow). 512 thr / 8 waves.
// K window staged ONCE into LDS (chunk-XOR swizzle, pre-swizzled global source);
// LDS reused: Kl -> Pl (P tile) -> ctx staging.
__global__ __launch_bounds__(512, 4) void attn_mfma(
    const short* __restrict__ qkv,
    const short* __restrict__ vt,
    short* __restrict__ ctxp,
    short* __restrict__ pb)     // [b][h][i][320] bf16
{
    __shared__ short Kl[64 * 320];   // 40,960 B: K stage -> P tile -> ctx tile
    __shared__ float Red[2][2][64];  //  1,024 B
    const int tid = threadIdx.x, w = tid >> 6, lane = tid & 63;
    const int quad = lane >> 4, mcol = lane & 15;
    const int id = blockIdx.x;
    const int i0 = (id >> 6) * 64, h = id & 15, b = (id >> 4) & 3;
    const int jb0 = i0 - 128;

    const short* qb = qkv + (size_t)(b * 1024) * 3072 + h * 64;
    const short* kb = qb + 1024;

    // ---- stage K window [jb0, jb0+320) x 64 into Kl (linear dest, pre-swizzled src) ----
    {
        short* dstb = Kl + w * 512;   // wave-uniform base; HW adds lane*16B
#pragma unroll
        for (int it = 0; it < 5; ++it) {
            int jo = it * 64 + w * 8 + (lane >> 3);
            int j  = min(max(jb0 + jo, 0), 1023);
            int g  = (lane & 7) ^ (jo & 7);
            async_copy16(kb + (size_t)j * 3072 + g * 8, dstb + it * 4096);
        }
    }

    // ---- Q frags (overlap with K DMA) ----
    const int mt = w >> 1, qtr = w & 1;
    const short* qrow = qb + (size_t)(i0 + mt * 16 + mcol) * 3072 + quad * 8;
    short8 aq0 = *(const short8*)qrow;
    short8 aq1 = *(const short8*)(qrow + 32);

    __syncthreads();   // drains vmcnt (K DMA + Q loads)

    // ---- QK^T from Kl ----
    floatx4 sacc[10];
#pragma unroll
    for (int c = 0; c < 10; ++c) sacc[c] = (floatx4){0.f, 0.f, 0.f, 0.f};
#pragma unroll
    for (int c = 0; c < 10; ++c) {
        int jo = qtr * 160 + c * 16 + mcol;
        const short* krow = Kl + jo * 64;
        short8 b0 = *(const short8*)&krow[((quad    ) ^ (jo & 7)) * 8];
        short8 b1 = *(const short8*)&krow[((4 + quad) ^ (jo & 7)) * 8];
        sacc[c] = __builtin_amdgcn_mfma_f32_16x16x32_bf16(aq0, b0, sacc[c], 0, 0, 0);
        sacc[c] = __builtin_amdgcn_mfma_f32_16x16x32_bf16(aq1, b1, sacc[c], 0, 0, 0);
    }

    // ---- mask+scale, half row-max (quad shuffles) ----
    const int row0 = mt * 16 + quad * 4;
#pragma unroll
    for (int r = 0; r < 4; ++r) {
        int row = row0 + r;
        float m = -1e30f;
#pragma unroll
        for (int c = 0; c < 10; ++c) {
            int jo = qtr * 160 + c * 16 + mcol;
            bool val = (jo >= row) && (jo <= row + 256) && ((unsigned)(jb0 + jo) < 1024u);
            float s = val ? sacc[c][r] * 0.125f : -1e30f;
            sacc[c][r] = s;
            m = fmaxf(m, s);
        }
        m = fmaxf(m, __shfl_xor(m, 1));
        m = fmaxf(m, __shfl_xor(m, 2));
        m = fmaxf(m, __shfl_xor(m, 4));
        m = fmaxf(m, __shfl_xor(m, 8));
        if (mcol == 0) Red[qtr][0][row] = m;
    }
    __syncthreads();
    // ---- exp + half row-sum ----
#pragma unroll
    for (int r = 0; r < 4; ++r) {
        int row = row0 + r;
        float M = fmaxf(Red[0][0][row], Red[1][0][row]);
        float l = 0.f;
#pragma unroll
        for (int c = 0; c < 10; ++c) {
            float p = __expf(sacc[c][r] - M);
            sacc[c][r] = p;
            l += p;
        }
        l += __shfl_xor(l, 1);
        l += __shfl_xor(l, 2);
        l += __shfl_xor(l, 4);
        l += __shfl_xor(l, 8);
        if (mcol == 0) Red[qtr][1][row] = l;
    }
    __syncthreads();   // all Kl reads done; safe to overwrite as Pl
    // ---- normalize, write P to swizzled LDS (aliases Kl) ----
    short* Pl = Kl;
#pragma unroll
    for (int r = 0; r < 4; ++r) {
        int row = row0 + r;
        float inv = 1.0f / (Red[0][1][row] + Red[1][1][row]);
#pragma unroll
        for (int c = 0; c < 10; ++c) {
            int jo = qtr * 160 + c * 16 + mcol;
            Pl[row * 320 + (((jo >> 3) ^ (row & 7)) * 8) + (jo & 7)] = f2bf(sacc[c][r] * inv);
        }
    }
    __syncthreads();

    // ---- PV (reads Pl + V direct from L2/L3) ----
    const int pmt = w & 3, dth = w >> 2;
    floatx4 cacc[2];
    cacc[0] = (floatx4){0.f, 0.f, 0.f, 0.f};
    cacc[1] = (floatx4){0.f, 0.f, 0.f, 0.f};
    const int prow = (pmt * 16 + mcol) * 320;
    const short* vb0 = vt + ((size_t)((b * 16 + h) * 64 + dth * 32) + mcol) * 1024;
#pragma unroll
    for (int jc = 0; jc < 10; ++jc) {
        short8 ap = *(const short8*)&Pl[prow + (((jc * 4 + quad) ^ (mcol & 7)) * 8)];
        int jg = jb0 + jc * 32 + quad * 8;
        if ((unsigned)jg >= 1024u) jg = 0;    // fully-masked frag (P=0)
        short8 bv0 = *(const short8*)(vb0 + jg);
        short8 bv1 = *(const short8*)(vb0 + (size_t)16 * 1024 + jg);
        cacc[0] = __builtin_amdgcn_mfma_f32_16x16x32_bf16(ap, bv0, cacc[0], 0, 0, 0);
        cacc[1] = __builtin_amdgcn_mfma_f32_16x16x32_bf16(ap, bv1, cacc[1], 0, 0, 0);
    }

    // ---- bulk P copy: Pl (un-swizzle) -> private pb region (contiguous) ----
    short* pbb = pb + ((size_t)((b * 16 + h) * 1024) + i0) * 320;
#pragma unroll
    for (int s = 0; s < 5; ++s) {
        int t = s * 512 + tid;
        int row = t / 40, c = t - row * 40;
        short8 v = *(const short8*)&Pl[row * 320 + ((c ^ (row & 7)) * 8)];
        *(short8*)&pbb[(size_t)t * 8] = v;     // t*8 == row*320 + c*8
    }
    __syncthreads();   // all Pl reads (PV frags + copy) complete

    // ---- ctx tile: regs -> LDS (stride 72, aliases Pl) -> coalesced rows ----
    short* Ct = Kl;
#pragma unroll
    for (int d2 = 0; d2 < 2; ++d2)
#pragma unroll
        for (int r = 0; r < 4; ++r)
            Ct[(pmt * 16 + quad * 4 + r) * 72 + dth * 32 + d2 * 16 + mcol] = f2bf(cacc[d2][r]);
    __syncthreads();
    short* cb = ctxp + (size_t)(b * 1024 + i0) * 1024 + h * 64;
    {
        int row = tid >> 3, c = tid & 7;
        short8 v = *(const short8*)&Ct[row * 72 + c * 8];
        *(short8*)&cb[(size_t)row * 1024 + c * 8] = v;
    }
}

// ---------------------------------------------------------------- head-mean reduce
__global__ __launch_bounds__(256) void pb_reduce(const short* __restrict__ pb,
                                                 float* __restrict__ aw)
{
    const int i = blockIdx.x & 1023, b = blockIdx.x >> 10;
    const int i0 = i & ~63;
    __shared__ short P[16 * 320];    // 10,240 B
    for (int t = threadIdx.x; t < 640; t += 256) {
        int hh = t / 40, c = t - hh * 40;
        ((short8*)P)[t] = *(const short8*)(pb +
            ((size_t)((b * 16 + hh) * 1024) + i) * 320 + c * 8);
    }
    __syncthreads();
    float* row = aw + ((size_t)(b * 1024) + i) * 1024;
    for (int j = threadIdx.x; j < 1024; j += 256) {
        int jo = j - i0 + 128;
        float s = 0.f;
        if ((unsigned)jo < 320u) {
#pragma unroll
            for (int hh = 0; hh < 16; ++hh)
                s += bf2f(P[hh * 320 + jo]);
            s *= (1.0f / 16.0f);
        }
        row[j] = s;
    }
}

// ---------------------------------------------------------------- launch
extern "C" void kernel_launch(void* const* d_in, const int* in_sizes, int n_in,
                              void* d_out, int out_size, void* d_ws, size_t ws_size,
                              hipStream_t stream) {
    const float* x    = (const float*)d_in[0];
    const float* wqkv = (const float*)d_in[1];
    const float* bqkv = (const float*)d_in[2];
    const float* wo   = (const float*)d_in[3];
    const float* bo   = (const float*)d_in[4];
    const float* g1   = (const float*)d_in[5];
    const float* be1  = (const float*)d_in[6];
    const float* w1   = (const float*)d_in[7];
    const float* bb1  = (const float*)d_in[8];
    const float* w2   = (const float*)d_in[9];
    const float* bb2  = (const float*)d_in[10];
    const float* g2   = (const float*)d_in[11];
    const float* be2  = (const float*)d_in[12];

    char* ws = (char*)d_ws;
    size_t off = 0;
    auto take = [&](size_t bytes) {
        void* p = ws + off;
        off += (bytes + 255) & ~(size_t)255;
        return p;
    };
    short* xb     = (short*)take((size_t)4096 * 1024 * 2);
    short* wqkv_b = (short*)take((size_t)3072 * 1024 * 2);
    short* wo_b   = (short*)take((size_t)1024 * 1024 * 2);
    short* w1_b   = (short*)take((size_t)4096 * 1024 * 2);
    short* w2_b   = (short*)take((size_t)1024 * 4096 * 2);
    short* qkv_b  = (short*)take((size_t)4096 * 3072 * 2);
    short* ctx_b  = (short*)take((size_t)4096 * 1024 * 2);
    short* ff2_p  = qkv_b;                                      // FFN2 bf16 partials x4
    short* attn_p = (short*)take((size_t)2 * 4096 * 1024 * 2);  // out-proj bf16 partials x2
    float* h_f    = (float*)take((size_t)4096 * 1024 * 4);
    short* vt_ws  = (short*)h_f;                                // vt dead before ln1 writes h_f
    short* h_b    = (short*)take((size_t)4096 * 1024 * 2);
    short* pb_ws  = (short*)take((size_t)4 * 16 * 1024 * 320 * 2);  // 41.9 MB
    short* ff_b   = pb_ws;                                      // FFN1 out aliases pb (33.6 <= 41.9)

    float* out_f = (float*)d_out;
    float* attnW = (float*)d_out + (size_t)4 * 1024 * 1024;

    // bf16 conversions (single launch)
    cvt5<<<16384, 256, 0, stream>>>(x, wqkv, wo, w1, w2, xb, wqkv_b, wo_b, w1_b, w2_b);

    // qkv projection -- 256x256 ring + phase pairs
    gemm256<false, false><<<dim3(16, 12), 512, 0, stream>>>(
        xb, wqkv_b, bqkv, qkv_b, 4096, 3072, 1024, 1024);

    // V transpose
    vtrans<<<1024, 256, 0, stream>>>(qkv_b, vt_ws);

    // banded attention (MFMA, register softmax, K staged in LDS); 64-row tiles
    attn_mfma<<<1024, 512, 0, stream>>>(qkv_b, vt_ws, ctx_b, pb_ws);

    // head-mean attention weights
    pb_reduce<<<4096, 256, 0, stream>>>(pb_ws, attnW);

    // out projection, split-K=2 -> bf16 partials
    gemm_bt<false, true><<<dim3(32, 8, 2), 256, 0, stream>>>(
        ctx_b, wo_b, nullptr, attn_p, 4096, 1024, 1024, 512);

    // h = LN(x + p0 + p1 + bo)
    ln_kernel<<<4096, 256, 0, stream>>>(x, attn_p, 2, bo, g1, be1, h_f, h_b);

    // FFN1 + ReLU -> bf16 -- 256x256 ring + phase pairs
    gemm256<true, false><<<dim3(16, 16), 512, 0, stream>>>(
        h_b, w1_b, bb1, ff_b, 4096, 4096, 1024, 1024);

    // FFN2, split-K=4 -> bf16 partials -- 256x256 ring + phase pairs
    gemm256<false, true><<<dim3(16, 4, 4), 512, 0, stream>>>(
        ff_b, w2_b, nullptr, ff2_p, 4096, 1024, 4096, 1024);

    // out = LN(h + p0..p3 + bb2)
    ln_kernel<<<4096, 256, 0, stream>>>(h_f, ff2_p, 4, bb2, g2, be2, out_f, nullptr);
}

// Round 6
// 321.959 us; speedup vs baseline: 1.0365x; 1.0365x over previous
//
#include <hip/hip_runtime.h>

// Shapes fixed by setup_inputs(): B=4, L=1024, E=1024, H=16, D=64, W=128
#define BB 4
#define LL 1024
#define EE 1024
#define HH 16
#define DD 64

typedef __attribute__((ext_vector_type(8))) short short8;
typedef __attribute__((ext_vector_type(4))) float floatx4;

#define PSTR ((size_t)4096 * 1024)   // split-K partial stride (elements, bf16)

__device__ __forceinline__ float bf2f(short s) {
    union { unsigned u; float f; } c;
    c.u = ((unsigned)(unsigned short)s) << 16;
    return c.f;
}
__device__ __forceinline__ short f2bf(float f) {
    union { float f; unsigned u; } c; c.f = f;
    unsigned r = c.u + 0x7fffu + ((c.u >> 16) & 1u);
    return (short)(r >> 16);
}

__device__ __forceinline__ void async_copy16(const void* g, void* l) {
    __builtin_amdgcn_global_load_lds(
        (const __attribute__((address_space(1))) unsigned int*)g,
        (__attribute__((address_space(3))) unsigned int*)l, 16, 0, 0);
}

// ---------------------------------------------------------------- convert (all 5 tensors, one launch)
__global__ __launch_bounds__(256) void cvt5(
    const float* __restrict__ x, const float* __restrict__ wqkv,
    const float* __restrict__ wo, const float* __restrict__ w1,
    const float* __restrict__ w2,
    short* __restrict__ xb, short* __restrict__ wqkvb, short* __restrict__ wob,
    short* __restrict__ w1b, short* __restrict__ w2b)
{
    int bi = blockIdx.x;
    const float* in; short* out; int base;
    if      (bi <  4096) { in = x;    out = xb;    base = 0;     }
    else if (bi <  7168) { in = wqkv; out = wqkvb; base = 4096;  }
    else if (bi <  8192) { in = wo;   out = wob;   base = 7168;  }
    else if (bi < 12288) { in = w1;   out = w1b;   base = 8192;  }
    else                 { in = w2;   out = w2b;   base = 12288; }
    int i = (bi - base) * 256 + threadIdx.x;
    float4 v = ((const float4*)in)[i];
    unsigned long long u =
          (unsigned long long)(unsigned short)f2bf(v.x)
        | ((unsigned long long)(unsigned short)f2bf(v.y) << 16)
        | ((unsigned long long)(unsigned short)f2bf(v.z) << 32)
        | ((unsigned long long)(unsigned short)f2bf(v.w) << 48);
    ((unsigned long long*)out)[i] = u;
}

// ---------------------------------------------------------------- GEMM 256x256 (NT), BK=64 minimal-sync
// C[m,n] = sum_k A[m,k]*B[n,k] (+bias). BM=BN=256, BK=64, 512 thr / 8 waves (2Mx4N).
// LDS: 2 buffers x (A 256x64 + B 256x64 bf16) = 128 KiB.
// Chunk swizzle: 16B chunk c of row r at position c^(r&7); pre-swizzled global src,
// linear gload_lds dest; frag reads are 2-way (free), 0 conflicts measured.
// Sync: ONE __syncthreads per K-tile (vmcnt0+lgkm0+barrier at loop top). Nothing
// younger than tile t is outstanding there, so the drain IS the counted wait.
// stage(t+1) issued immediately after -> in flight for a FULL tile body (>2000 cyc
// >> ~900 cyc HBM). No mid-tile barriers: stage writes the OTHER buffer; the
// loop-top barrier of t guarantees all waves done reading t-1 before anyone
// stages t+1 into buf (t+1)&1 == (t-1)&1. Cross-wave overlap (2 waves/SIMD,
// setprio on MFMA clusters) hides each wave's own read-wait.
template<bool RELU, bool SK>
__global__ __launch_bounds__(512, 2) void gemm256(
    const short* __restrict__ A, const short* __restrict__ Bw,
    const float* __restrict__ bias,
    short* __restrict__ Cb,
    int M, int N, int K, int Ksp)
{
    __shared__ short SH[67584];   // union{ 2 bufs 131072 B ; C stage 256x264x2 = 135168 B }
    const int tid  = threadIdx.x;
    const int w    = tid >> 6, lane = tid & 63;
    const int fr   = lane & 15, quad = lane >> 4;
    const int wm   = w >> 2,  wn   = w & 3;

    // XCD-bijective block swizzle (all grids have nwg % 8 == 0)
    const int gx   = gridDim.x;                 // = M-tiles
    const int flat = blockIdx.y * gx + blockIdx.x;
    const int nwg  = gx * gridDim.y;
    const int q8   = nwg >> 3;
    const int swz  = (flat & 7) * q8 + (flat >> 3);
    const int m0   = (swz % gx) * 256;
    const int n0   = (swz / gx) * 256;

    const int kb = SK ? blockIdx.z * Ksp : 0;
    const int NT = (SK ? Ksp : K) >> 6;

    // staging: 256x64x2B = 32 KiB per tensor per tile -> 4x16B per thread each.
    // slot (16B units) = i*512 + w*64 + lane -> row r = i*64 + w*8 + (lane>>3),
    // dest chunk c = lane&7, source chunk g = c ^ (r&7).
    const int srow = w * 8 + (lane >> 3);
    const int sg   = lane & 7;
    auto stage = [&](int s) {
        if (s >= NT) return;
#pragma unroll
        for (int i = 0; i < 4; ++i) {
            int r = i * 64 + srow;
            int g = sg ^ (r & 7);
            async_copy16(A + (size_t)(m0 + r) * K + kb + s * 64 + g * 8,
                         SH + (s & 1) * 32768 + i * 4096 + w * 512);
        }
#pragma unroll
        for (int i = 0; i < 4; ++i) {
            int r = i * 64 + srow;
            int g = sg ^ (r & 7);
            async_copy16(Bw + (size_t)(n0 + r) * K + kb + s * 64 + g * 8,
                         SH + (s & 1) * 32768 + 16384 + i * 4096 + w * 512);
        }
    };

    floatx4 acc[8][4];
#pragma unroll
    for (int i = 0; i < 8; ++i)
#pragma unroll
        for (int j = 0; j < 4; ++j) acc[i][j] = (floatx4){0.f, 0.f, 0.f, 0.f};

    // prologue: stage tile 0 only (first-tile latency exposed once)
    stage(0);

    const int posk0 = ((quad    ) ^ (fr & 7)) * 8;   // ks=0 chunk position
    const int posk1 = ((4 + quad) ^ (fr & 7)) * 8;   // ks=1 chunk position

    for (int t = 0; t < NT; ++t) {
        __syncthreads();   // vmcnt0+lgkm0+barrier: buf[t] landed, t-1 reads done everywhere
        __builtin_amdgcn_sched_barrier(0);

        const short* sA = SH + (t & 1) * 32768;
        const short* sB = sA + 16384;

        stage(t + 1);      // 8 DMA into the other buffer; in flight for the whole tile

        short8 a0[8], b0[4];
#pragma unroll
        for (int i = 0; i < 8; ++i) a0[i] = *(const short8*)&sA[(wm * 128 + i * 16 + fr) * 64 + posk0];
#pragma unroll
        for (int j = 0; j < 4; ++j) b0[j] = *(const short8*)&sB[(wn * 64 + j * 16 + fr) * 64 + posk0];
        __builtin_amdgcn_s_setprio(1);
#pragma unroll
        for (int i = 0; i < 8; ++i)
#pragma unroll
            for (int j = 0; j < 4; ++j)
                acc[i][j] = __builtin_amdgcn_mfma_f32_16x16x32_bf16(a0[i], b0[j], acc[i][j], 0, 0, 0);
        __builtin_amdgcn_s_setprio(0);

        short8 a1[8], b1[4];
#pragma unroll
        for (int i = 0; i < 8; ++i) a1[i] = *(const short8*)&sA[(wm * 128 + i * 16 + fr) * 64 + posk1];
#pragma unroll
        for (int j = 0; j < 4; ++j) b1[j] = *(const short8*)&sB[(wn * 64 + j * 16 + fr) * 64 + posk1];
        __builtin_amdgcn_s_setprio(1);
#pragma unroll
        for (int i = 0; i < 8; ++i)
#pragma unroll
            for (int j = 0; j < 4; ++j)
                acc[i][j] = __builtin_amdgcn_mfma_f32_16x16x32_bf16(a1[i], b1[j], acc[i][j], 0, 0, 0);
        __builtin_amdgcn_s_setprio(0);
    }

    __syncthreads();   // all reads done, no DMA outstanding; LDS reused for C staging

    // ---- epilogue: acc -> LDS bf16 [256][264] -> coalesced short8 global rows
    const int cc = lane & 15, rb4 = quad * 4;
#pragma unroll
    for (int i = 0; i < 8; ++i) {
        int row = wm * 128 + i * 16 + rb4;
#pragma unroll
        for (int j = 0; j < 4; ++j) {
            int col = wn * 64 + j * 16 + cc;
            float bv = SK ? 0.0f : bias[n0 + col];
#pragma unroll
            for (int r = 0; r < 4; ++r) {
                float v = acc[i][j][r] + bv;
                if (RELU) v = fmaxf(v, 0.0f);
                SH[(row + r) * 264 + col] = f2bf(v);
            }
        }
    }
    __syncthreads();
    short* Co = Cb + (SK ? (size_t)blockIdx.z * PSTR : 0);
#pragma unroll
    for (int it = 0; it < 16; ++it) {
        int idx = it * 512 + tid;
        int row = idx >> 5, ch = idx & 31;
        short8 v = *(const short8*)&SH[row * 264 + ch * 8];
        *(short8*)&Co[(size_t)(m0 + row) * N + n0 + ch * 8] = v;
    }
}

// ---------------------------------------------------------------- V transpose
// vt[((b*16+h)*64+d)*1024 + tok] = qkv[(b*1024+tok)*3072 + 2048 + h*64 + d]
__global__ __launch_bounds__(256) void vtrans(const short* __restrict__ qkv,
                                              short* __restrict__ vt)
{
    int id = blockIdx.x;                 // 1024 = 4b * 16h * 16 tok-blocks
    int tb = id & 15, h = (id >> 4) & 15, b = id >> 8;
    __shared__ short T[64 * 72];
    const short* src = qkv + (size_t)(b * 1024 + tb * 64) * 3072 + 2048 + h * 64;
    int tok = threadIdx.x >> 2;
    int c8  = threadIdx.x & 3;
#pragma unroll
    for (int q = 0; q < 2; ++q) {
        int d0 = (c8 * 2 + q) * 8;
        short8 v = *(const short8*)&src[(size_t)tok * 3072 + d0];
#pragma unroll
        for (int e = 0; e < 8; ++e) T[(d0 + e) * 72 + tok] = v[e];
    }
    __syncthreads();
    short* dst = vt + (size_t)((b * 16 + h) * 64) * 1024 + tb * 64;
    int d = threadIdx.x >> 2, cq = threadIdx.x & 3;
#pragma unroll
    for (int q = 0; q < 2; ++q) {
        int t0 = (cq * 2 + q) * 8;
        *(short8*)&dst[(size_t)d * 1024 + t0] = *(const short8*)&T[d * 72 + t0];
    }
}

// ---------------------------------------------------------------- GEMM (NT) 128x128 (out-proj)
template<bool RELU, bool SK>
__global__ __launch_bounds__(256) void gemm_bt(
    const short* __restrict__ A, const short* __restrict__ Bw,
    const float* __restrict__ bias,
    short* __restrict__ Cb,
    int M, int N, int K, int Ksp)
{
    __shared__ union U {
        struct { short As[128 * 64]; short Bs[128 * 64]; } s;
        short Cs[128 * 136];
    } u;
    const int tid  = threadIdx.x;
    const int wave = tid >> 6, lane = tid & 63;
    const int m0 = blockIdx.x * 128, n0 = blockIdx.y * 128;
    const int wm = (wave & 1) * 64, wn = (wave >> 1) * 64;
    const int kbase = SK ? blockIdx.z * Ksp : 0;

    floatx4 acc[4][4];
#pragma unroll
    for (int i = 0; i < 4; ++i)
#pragma unroll
        for (int j = 0; j < 4; ++j) acc[i][j] = (floatx4){0.f, 0.f, 0.f, 0.f};

    const int srow = wave * 8 + (lane >> 3);
    const int scol = (((lane & 7) ^ ((lane >> 3) & 7))) * 8;
    const short* gA = A  + (size_t)(m0 + srow) * K + kbase + scol;
    const short* gB = Bw + (size_t)(n0 + srow) * K + kbase + scol;
    short* lA = u.s.As + wave * 512;
    short* lB = u.s.Bs + wave * 512;

    const int fr = lane & 15, quad = lane >> 4;
    const int kiters = (SK ? Ksp : K) >> 6;
    for (int kt = 0; kt < kiters; ++kt) {
#pragma unroll
        for (int s = 0; s < 4; ++s) {
            async_copy16(gA + (size_t)s * 32 * K, lA + s * 2048);
            async_copy16(gB + (size_t)s * 32 * K, lB + s * 2048);
        }
        gA += 64; gB += 64;
        __syncthreads();
#pragma unroll
        for (int ks = 0; ks < 2; ++ks) {
            short8 af[4], bf[4];
#pragma unroll
            for (int i = 0; i < 4; ++i) {
                int pos = ((ks * 4 + quad) ^ (fr & 7)) * 8;
                af[i] = *(const short8*)&u.s.As[(wm + i * 16 + fr) * 64 + pos];
                bf[i] = *(const short8*)&u.s.Bs[(wn + i * 16 + fr) * 64 + pos];
            }
#pragma unroll
            for (int i = 0; i < 4; ++i)
#pragma unroll
                for (int j = 0; j < 4; ++j)
                    acc[i][j] = __builtin_amdgcn_mfma_f32_16x16x32_bf16(af[i], bf[j], acc[i][j], 0, 0, 0);
        }
        __syncthreads();
    }

    const int cc = lane & 15;
    const int rb = (lane >> 4) * 4;
#pragma unroll
    for (int j = 0; j < 4; ++j) {
        int col = wn + j * 16 + cc;
        float bv = SK ? 0.0f : bias[n0 + col];
#pragma unroll
        for (int i = 0; i < 4; ++i) {
            int row = wm + i * 16 + rb;
#pragma unroll
            for (int r = 0; r < 4; ++r) {
                float v = acc[i][j][r] + bv;
                if (RELU) v = fmaxf(v, 0.0f);
                u.Cs[(row + r) * 136 + col] = f2bf(v);
            }
        }
    }
    __syncthreads();
    short* Co = Cb + (SK ? (size_t)blockIdx.z * PSTR : 0);
    const int trow = tid >> 4, tcol = (tid & 15) * 8;
#pragma unroll
    for (int p = 0; p < 8; ++p) {
        int row = p * 16 + trow;
        short8 vv = *(const short8*)&u.Cs[row * 136 + tcol];
        *(short8*)&Co[(size_t)(m0 + row) * N + n0 + tcol] = vv;
    }
}

// ---------------------------------------------------------------- LayerNorm
__global__ __launch_bounds__(256) void ln_kernel(
    const float* __restrict__ xa, const short* __restrict__ parts, int nparts,
    const float* __restrict__ bias,
    const float* __restrict__ g, const float* __restrict__ beta,
    float* __restrict__ outf, short* __restrict__ outb)
{
    const int row = blockIdx.x;
    const int tid = threadIdx.x;
    float4 va = ((const float4*)(xa + (size_t)row * EE))[tid];
    float4 vb = ((const float4*)bias)[tid];
    float v0 = va.x + vb.x, v1 = va.y + vb.y, v2 = va.z + vb.z, v3 = va.w + vb.w;
#pragma unroll 4
    for (int p = 0; p < nparts; ++p) {
        unsigned long long u8 = ((const unsigned long long*)(parts + p * PSTR + (size_t)row * EE))[tid];
        v0 += bf2f((short)(u8 & 0xffff));
        v1 += bf2f((short)((u8 >> 16) & 0xffff));
        v2 += bf2f((short)((u8 >> 32) & 0xffff));
        v3 += bf2f((short)(u8 >> 48));
    }
    float s  = v0 + v1 + v2 + v3;
    float ss = v0 * v0 + v1 * v1 + v2 * v2 + v3 * v3;
#pragma unroll
    for (int o = 1; o < 64; o <<= 1) { s += __shfl_xor(s, o); ss += __shfl_xor(ss, o); }
    __shared__ float red[8];
    if ((tid & 63) == 0) { red[(tid >> 6) * 2] = s; red[(tid >> 6) * 2 + 1] = ss; }
    __syncthreads();
    s  = red[0] + red[2] + red[4] + red[6];
    ss = red[1] + red[3] + red[5] + red[7];
    float mean = s * (1.0f / EE);
    float var  = ss * (1.0f / EE) - mean * mean;
    float rstd = rsqrtf(var + 1e-5f);
    float4 vg = ((const float4*)g)[tid];
    float4 vt = ((const float4*)beta)[tid];
    float o0 = (v0 - mean) * rstd * vg.x + vt.x;
    float o1 = (v1 - mean) * rstd * vg.y + vt.y;
    float o2 = (v2 - mean) * rstd * vg.z + vt.z;
    float o3 = (v3 - mean) * rstd * vg.w + vt.w;
    if (outf) ((float4*)(outf + (size_t)row * EE))[tid] = make_float4(o0, o1, o2, o3);
    if (outb) {
        unsigned long long u =
              (unsigned long long)(unsigned short)f2bf(o0)
            | ((unsigned long long)(unsigned short)f2bf(o1) << 16)
            | ((unsigned long long)(unsigned short)f2bf(o2) << 32)
            | ((unsigned long long)(unsigned short)f2bf(o3) << 48);
        ((unsigned long long*)(outb + (size_t)row * EE))[tid] = u;
    }
}

// ---------------------------------------------------------------- attention (MFMA, register softmax)
// 64-row i-tile per block (same 320-col K window serves all 64 rows since 64+2*128=320).
// Grid 1024 = 16 i-tiles x 4b x 16h (i0 slow). 512 thr / 8 waves.
// K window staged ONCE into LDS (chunk-XOR swizzle, pre-swizzled global source);
// LDS reused: Kl -> Pl (P tile) -> ctx staging.
__global__ __launch_bounds__(512, 4) void attn_mfma(
    const short* __restrict__ qkv,
    const short* __restrict__ vt,
    short* __restrict__ ctxp,
    short* __restrict__ pb)     // [b][h][i][320] bf16
{
    __shared__ short Kl[64 * 320];   // 40,960 B: K stage -> P tile -> ctx tile
    __shared__ float Red[2][2][64];  //  1,024 B
    const int tid = threadIdx.x, w = tid >> 6, lane = tid & 63;
    const int quad = lane >> 4, mcol = lane & 15;
    const int id = blockIdx.x;
    const int i0 = (id >> 6) * 64, h = id & 15, b = (id >> 4) & 3;
    const int jb0 = i0 - 128;

    const short* qb = qkv + (size_t)(b * 1024) * 3072 + h * 64;
    const short* kb = qb + 1024;

    // ---- stage K window [jb0, jb0+320) x 64 into Kl (linear dest, pre-swizzled src) ----
    {
        short* dstb = Kl + w * 512;   // wave-uniform base; HW adds lane*16B
#pragma unroll
        for (int it = 0; it < 5; ++it) {
            int jo = it * 64 + w * 8 + (lane >> 3);
            int j  = min(max(jb0 + jo, 0), 1023);
            int g  = (lane & 7) ^ (jo & 7);
            async_copy16(kb + (size_t)j * 3072 + g * 8, dstb + it * 4096);
        }
    }

    // ---- Q frags (overlap with K DMA) ----
    const int mt = w >> 1, qtr = w & 1;
    const short* qrow = qb + (size_t)(i0 + mt * 16 + mcol) * 3072 + quad * 8;
    short8 aq0 = *(const short8*)qrow;
    short8 aq1 = *(const short8*)(qrow + 32);

    __syncthreads();   // drains vmcnt (K DMA + Q loads)

    // ---- QK^T from Kl ----
    floatx4 sacc[10];
#pragma unroll
    for (int c = 0; c < 10; ++c) sacc[c] = (floatx4){0.f, 0.f, 0.f, 0.f};
#pragma unroll
    for (int c = 0; c < 10; ++c) {
        int jo = qtr * 160 + c * 16 + mcol;
        const short* krow = Kl + jo * 64;
        short8 b0 = *(const short8*)&krow[((quad    ) ^ (jo & 7)) * 8];
        short8 b1 = *(const short8*)&krow[((4 + quad) ^ (jo & 7)) * 8];
        sacc[c] = __builtin_amdgcn_mfma_f32_16x16x32_bf16(aq0, b0, sacc[c], 0, 0, 0);
        sacc[c] = __builtin_amdgcn_mfma_f32_16x16x32_bf16(aq1, b1, sacc[c], 0, 0, 0);
    }

    // ---- mask+scale, half row-max (quad shuffles) ----
    const int row0 = mt * 16 + quad * 4;
#pragma unroll
    for (int r = 0; r < 4; ++r) {
        int row = row0 + r;
        float m = -1e30f;
#pragma unroll
        for (int c = 0; c < 10; ++c) {
            int jo = qtr * 160 + c * 16 + mcol;
            bool val = (jo >= row) && (jo <= row + 256) && ((unsigned)(jb0 + jo) < 1024u);
            float s = val ? sacc[c][r] * 0.125f : -1e30f;
            sacc[c][r] = s;
            m = fmaxf(m, s);
        }
        m = fmaxf(m, __shfl_xor(m, 1));
        m = fmaxf(m, __shfl_xor(m, 2));
        m = fmaxf(m, __shfl_xor(m, 4));
        m = fmaxf(m, __shfl_xor(m, 8));
        if (mcol == 0) Red[qtr][0][row] = m;
    }
    __syncthreads();
    // ---- exp + half row-sum ----
#pragma unroll
    for (int r = 0; r < 4; ++r) {
        int row = row0 + r;
        float M = fmaxf(Red[0][0][row], Red[1][0][row]);
        float l = 0.f;
#pragma unroll
        for (int c = 0; c < 10; ++c) {
            float p = __expf(sacc[c][r] - M);
            sacc[c][r] = p;
            l += p;
        }
        l += __shfl_xor(l, 1);
        l += __shfl_xor(l, 2);
        l += __shfl_xor(l, 4);
        l += __shfl_xor(l, 8);
        if (mcol == 0) Red[qtr][1][row] = l;
    }
    __syncthreads();   // all Kl reads done; safe to overwrite as Pl
    // ---- normalize, write P to swizzled LDS (aliases Kl) ----
    short* Pl = Kl;
#pragma unroll
    for (int r = 0; r < 4; ++r) {
        int row = row0 + r;
        float inv = 1.0f / (Red[0][1][row] + Red[1][1][row]);
#pragma unroll
        for (int c = 0; c < 10; ++c) {
            int jo = qtr * 160 + c * 16 + mcol;
            Pl[row * 320 + (((jo >> 3) ^ (row & 7)) * 8) + (jo & 7)] = f2bf(sacc[c][r] * inv);
        }
    }
    __syncthreads();

    // ---- PV (reads Pl + V direct from L2/L3) ----
    const int pmt = w & 3, dth = w >> 2;
    floatx4 cacc[2];
    cacc[0] = (floatx4){0.f, 0.f, 0.f, 0.f};
    cacc[1] = (floatx4){0.f, 0.f, 0.f, 0.f};
    const int prow = (pmt * 16 + mcol) * 320;
    const short* vb0 = vt + ((size_t)((b * 16 + h) * 64 + dth * 32) + mcol) * 1024;
#pragma unroll
    for (int jc = 0; jc < 10; ++jc) {
        short8 ap = *(const short8*)&Pl[prow + (((jc * 4 + quad) ^ (mcol & 7)) * 8)];
        int jg = jb0 + jc * 32 + quad * 8;
        if ((unsigned)jg >= 1024u) jg = 0;    // fully-masked frag (P=0)
        short8 bv0 = *(const short8*)(vb0 + jg);
        short8 bv1 = *(const short8*)(vb0 + (size_t)16 * 1024 + jg);
        cacc[0] = __builtin_amdgcn_mfma_f32_16x16x32_bf16(ap, bv0, cacc[0], 0, 0, 0);
        cacc[1] = __builtin_amdgcn_mfma_f32_16x16x32_bf16(ap, bv1, cacc[1], 0, 0, 0);
    }

    // ---- bulk P copy: Pl (un-swizzle) -> private pb region (contiguous) ----
    short* pbb = pb + ((size_t)((b * 16 + h) * 1024) + i0) * 320;
#pragma unroll
    for (int s = 0; s < 5; ++s) {
        int t = s * 512 + tid;
        int row = t / 40, c = t - row * 40;
        short8 v = *(const short8*)&Pl[row * 320 + ((c ^ (row & 7)) * 8)];
        *(short8*)&pbb[(size_t)t * 8] = v;     // t*8 == row*320 + c*8
    }
    __syncthreads();   // all Pl reads (PV frags + copy) complete

    // ---- ctx tile: regs -> LDS (stride 72, aliases Pl) -> coalesced rows ----
    short* Ct = Kl;
#pragma unroll
    for (int d2 = 0; d2 < 2; ++d2)
#pragma unroll
        for (int r = 0; r < 4; ++r)
            Ct[(pmt * 16 + quad * 4 + r) * 72 + dth * 32 + d2 * 16 + mcol] = f2bf(cacc[d2][r]);
    __syncthreads();
    short* cb = ctxp + (size_t)(b * 1024 + i0) * 1024 + h * 64;
    {
        int row = tid >> 3, c = tid & 7;
        short8 v = *(const short8*)&Ct[row * 72 + c * 8];
        *(short8*)&cb[(size_t)row * 1024 + c * 8] = v;
    }
}

// ---------------------------------------------------------------- head-mean reduce
__global__ __launch_bounds__(256) void pb_reduce(const short* __restrict__ pb,
                                                 float* __restrict__ aw)
{
    const int i = blockIdx.x & 1023, b = blockIdx.x >> 10;
    const int i0 = i & ~63;
    __shared__ short P[16 * 320];    // 10,240 B
    for (int t = threadIdx.x; t < 640; t += 256) {
        int hh = t / 40, c = t - hh * 40;
        ((short8*)P)[t] = *(const short8*)(pb +
            ((size_t)((b * 16 + hh) * 1024) + i) * 320 + c * 8);
    }
    __syncthreads();
    float* row = aw + ((size_t)(b * 1024) + i) * 1024;
    for (int j = threadIdx.x; j < 1024; j += 256) {
        int jo = j - i0 + 128;
        float s = 0.f;
        if ((unsigned)jo < 320u) {
#pragma unroll
            for (int hh = 0; hh < 16; ++hh)
                s += bf2f(P[hh * 320 + jo]);
            s *= (1.0f / 16.0f);
        }
        row[j] = s;
    }
}

// ---------------------------------------------------------------- launch
extern "C" void kernel_launch(void* const* d_in, const int* in_sizes, int n_in,
                              void* d_out, int out_size, void* d_ws, size_t ws_size,
                              hipStream_t stream) {
    const float* x    = (const float*)d_in[0];
    const float* wqkv = (const float*)d_in[1];
    const float* bqkv = (const float*)d_in[2];
    const float* wo   = (const float*)d_in[3];
    const float* bo   = (const float*)d_in[4];
    const float* g1   = (const float*)d_in[5];
    const float* be1  = (const float*)d_in[6];
    const float* w1   = (const float*)d_in[7];
    const float* bb1  = (const float*)d_in[8];
    const float* w2   = (const float*)d_in[9];
    const float* bb2  = (const float*)d_in[10];
    const float* g2   = (const float*)d_in[11];
    const float* be2  = (const float*)d_in[12];

    char* ws = (char*)d_ws;
    size_t off = 0;
    auto take = [&](size_t bytes) {
        void* p = ws + off;
        off += (bytes + 255) & ~(size_t)255;
        return p;
    };
    short* xb     = (short*)take((size_t)4096 * 1024 * 2);
    short* wqkv_b = (short*)take((size_t)3072 * 1024 * 2);
    short* wo_b   = (short*)take((size_t)1024 * 1024 * 2);
    short* w1_b   = (short*)take((size_t)4096 * 1024 * 2);
    short* w2_b   = (short*)take((size_t)1024 * 4096 * 2);
    short* qkv_b  = (short*)take((size_t)4096 * 3072 * 2);
    short* ctx_b  = (short*)take((size_t)4096 * 1024 * 2);
    short* ff2_p  = qkv_b;                                      // FFN2 bf16 partials x4
    short* attn_p = (short*)take((size_t)2 * 4096 * 1024 * 2);  // out-proj bf16 partials x2
    float* h_f    = (float*)take((size_t)4096 * 1024 * 4);
    short* vt_ws  = (short*)h_f;                                // vt dead before ln1 writes h_f
    short* h_b    = (short*)take((size_t)4096 * 1024 * 2);
    short* pb_ws  = (short*)take((size_t)4 * 16 * 1024 * 320 * 2);  // 41.9 MB
    short* ff_b   = pb_ws;                                      // FFN1 out aliases pb (33.6 <= 41.9)

    float* out_f = (float*)d_out;
    float* attnW = (float*)d_out + (size_t)4 * 1024 * 1024;

    // bf16 conversions (single launch)
    cvt5<<<16384, 256, 0, stream>>>(x, wqkv, wo, w1, w2, xb, wqkv_b, wo_b, w1_b, w2_b);

    // qkv projection -- 256x256 BK=64 minimal-sync
    gemm256<false, false><<<dim3(16, 12), 512, 0, stream>>>(
        xb, wqkv_b, bqkv, qkv_b, 4096, 3072, 1024, 1024);

    // V transpose
    vtrans<<<1024, 256, 0, stream>>>(qkv_b, vt_ws);

    // banded attention (MFMA, register softmax, K staged in LDS); 64-row tiles
    attn_mfma<<<1024, 512, 0, stream>>>(qkv_b, vt_ws, ctx_b, pb_ws);

    // head-mean attention weights
    pb_reduce<<<4096, 256, 0, stream>>>(pb_ws, attnW);

    // out projection, split-K=2 -> bf16 partials
    gemm_bt<false, true><<<dim3(32, 8, 2), 256, 0, stream>>>(
        ctx_b, wo_b, nullptr, attn_p, 4096, 1024, 1024, 512);

    // h = LN(x + p0 + p1 + bo)
    ln_kernel<<<4096, 256, 0, stream>>>(x, attn_p, 2, bo, g1, be1, h_f, h_b);

    // FFN1 + ReLU -> bf16 -- 256x256 BK=64 minimal-sync
    gemm256<true, false><<<dim3(16, 16), 512, 0, stream>>>(
        h_b, w1_b, bb1, ff_b, 4096, 4096, 1024, 1024);

    // FFN2, split-K=4 -> bf16 partials -- 256x256 BK=64 minimal-sync
    gemm256<false, true><<<dim3(16, 4, 4), 512, 0, stream>>>(
        ff_b, w2_b, nullptr, ff2_p, 4096, 1024, 4096, 1024);

    // out = LN(h + p0..p3 + bb2)
    ln_kernel<<<4096, 256, 0, stream>>>(h_f, ff2_p, 4, bb2, g2, be2, out_f, nullptr);
}

// Round 7
// 320.878 us; speedup vs baseline: 1.0400x; 1.0034x over previous
//
#include <hip/hip_runtime.h>

// Shapes fixed by setup_inputs(): B=4, L=1024, E=1024, H=16, D=64, W=128
#define BB 4
#define LL 1024
#define EE 1024
#define HH 16
#define DD 64

typedef __attribute__((ext_vector_type(8))) short short8;
typedef __attribute__((ext_vector_type(4))) float floatx4;

#define PSTR ((size_t)4096 * 1024)   // split-K partial stride (elements, bf16)

__device__ __forceinline__ float bf2f(short s) {
    union { unsigned u; float f; } c;
    c.u = ((unsigned)(unsigned short)s) << 16;
    return c.f;
}
__device__ __forceinline__ short f2bf(float f) {
    union { float f; unsigned u; } c; c.f = f;
    unsigned r = c.u + 0x7fffu + ((c.u >> 16) & 1u);
    return (short)(r >> 16);
}

__device__ __forceinline__ void async_copy16(const void* g, void* l) {
    __builtin_amdgcn_global_load_lds(
        (const __attribute__((address_space(1))) unsigned int*)g,
        (__attribute__((address_space(3))) unsigned int*)l, 16, 0, 0);
}

// ---------------------------------------------------------------- convert (all 5 tensors, one launch)
__global__ __launch_bounds__(256) void cvt5(
    const float* __restrict__ x, const float* __restrict__ wqkv,
    const float* __restrict__ wo, const float* __restrict__ w1,
    const float* __restrict__ w2,
    short* __restrict__ xb, short* __restrict__ wqkvb, short* __restrict__ wob,
    short* __restrict__ w1b, short* __restrict__ w2b)
{
    int bi = blockIdx.x;
    const float* in; short* out; int base;
    if      (bi <  4096) { in = x;    out = xb;    base = 0;     }
    else if (bi <  7168) { in = wqkv; out = wqkvb; base = 4096;  }
    else if (bi <  8192) { in = wo;   out = wob;   base = 7168;  }
    else if (bi < 12288) { in = w1;   out = w1b;   base = 8192;  }
    else                 { in = w2;   out = w2b;   base = 12288; }
    int i = (bi - base) * 256 + threadIdx.x;
    float4 v = ((const float4*)in)[i];
    unsigned long long u =
          (unsigned long long)(unsigned short)f2bf(v.x)
        | ((unsigned long long)(unsigned short)f2bf(v.y) << 16)
        | ((unsigned long long)(unsigned short)f2bf(v.z) << 32)
        | ((unsigned long long)(unsigned short)f2bf(v.w) << 48);
    ((unsigned long long*)out)[i] = u;
}

// ---------------------------------------------------------------- GEMM 256x256 (NT), BK=64 minimal-sync
// C[m,n] = sum_k A[m,k]*B[n,k] (+bias). BM=BN=256, BK=64, 512 thr / 8 waves (2Mx4N).
// LDS: 2 buffers x (A 256x64 + B 256x64 bf16) = 128 KiB.
// Chunk swizzle: 16B chunk c of row r at position c^(r&7); pre-swizzled global src,
// linear gload_lds dest; frag reads are 2-way (free), 0 conflicts measured.
// Sync: ONE __syncthreads per K-tile (vmcnt0+lgkm0+barrier at loop top); stage(t+1)
// issued right after -> in flight for a full tile body (>2000 cyc >> ~900 HBM).
// WVT (qkv only): V-column blocks (n0>=2048, uniform) write acc TRANSPOSED into the
// C-stage LDS as Vt[col][row] (stride 264) then store coalesced rows into vt;
// their qkv_b row-stores are skipped (nothing reads V rows once vt exists).
template<bool RELU, bool SK, bool WVT>
__global__ __launch_bounds__(512, 2) void gemm256(
    const short* __restrict__ A, const short* __restrict__ Bw,
    const float* __restrict__ bias,
    short* __restrict__ Cb, short* __restrict__ VTp,
    int M, int N, int K, int Ksp)
{
    __shared__ short SH[67584];   // union{ 2 bufs 131072 B ; C/Vt stage 256x264x2 = 135168 B }
    const int tid  = threadIdx.x;
    const int w    = tid >> 6, lane = tid & 63;
    const int fr   = lane & 15, quad = lane >> 4;
    const int wm   = w >> 2,  wn   = w & 3;

    // XCD-bijective block swizzle (all grids have nwg % 8 == 0)
    const int gx   = gridDim.x;                 // = M-tiles
    const int flat = blockIdx.y * gx + blockIdx.x;
    const int nwg  = gx * gridDim.y;
    const int q8   = nwg >> 3;
    const int swz  = (flat & 7) * q8 + (flat >> 3);
    const int m0   = (swz % gx) * 256;
    const int n0   = (swz / gx) * 256;

    const int kb = SK ? blockIdx.z * Ksp : 0;
    const int NT = (SK ? Ksp : K) >> 6;

    // staging: 256x64x2B = 32 KiB per tensor per tile -> 4x16B per thread each.
    // slot (16B units) = i*512 + w*64 + lane -> row r = i*64 + w*8 + (lane>>3),
    // dest chunk c = lane&7, source chunk g = c ^ (r&7).
    const int srow = w * 8 + (lane >> 3);
    const int sg   = lane & 7;
    auto stage = [&](int s) {
        if (s >= NT) return;
#pragma unroll
        for (int i = 0; i < 4; ++i) {
            int r = i * 64 + srow;
            int g = sg ^ (r & 7);
            async_copy16(A + (size_t)(m0 + r) * K + kb + s * 64 + g * 8,
                         SH + (s & 1) * 32768 + i * 4096 + w * 512);
        }
#pragma unroll
        for (int i = 0; i < 4; ++i) {
            int r = i * 64 + srow;
            int g = sg ^ (r & 7);
            async_copy16(Bw + (size_t)(n0 + r) * K + kb + s * 64 + g * 8,
                         SH + (s & 1) * 32768 + 16384 + i * 4096 + w * 512);
        }
    };

    floatx4 acc[8][4];
#pragma unroll
    for (int i = 0; i < 8; ++i)
#pragma unroll
        for (int j = 0; j < 4; ++j) acc[i][j] = (floatx4){0.f, 0.f, 0.f, 0.f};

    // prologue: stage tile 0 only (first-tile latency exposed once)
    stage(0);

    const int posk0 = ((quad    ) ^ (fr & 7)) * 8;   // ks=0 chunk position
    const int posk1 = ((4 + quad) ^ (fr & 7)) * 8;   // ks=1 chunk position

    for (int t = 0; t < NT; ++t) {
        __syncthreads();   // vmcnt0+lgkm0+barrier: buf[t] landed, t-1 reads done everywhere
        __builtin_amdgcn_sched_barrier(0);

        const short* sA = SH + (t & 1) * 32768;
        const short* sB = sA + 16384;

        stage(t + 1);      // 8 DMA into the other buffer; in flight for the whole tile

        short8 a0[8], b0[4];
#pragma unroll
        for (int i = 0; i < 8; ++i) a0[i] = *(const short8*)&sA[(wm * 128 + i * 16 + fr) * 64 + posk0];
#pragma unroll
        for (int j = 0; j < 4; ++j) b0[j] = *(const short8*)&sB[(wn * 64 + j * 16 + fr) * 64 + posk0];
        __builtin_amdgcn_s_setprio(1);
#pragma unroll
        for (int i = 0; i < 8; ++i)
#pragma unroll
            for (int j = 0; j < 4; ++j)
                acc[i][j] = __builtin_amdgcn_mfma_f32_16x16x32_bf16(a0[i], b0[j], acc[i][j], 0, 0, 0);
        __builtin_amdgcn_s_setprio(0);

        short8 a1[8], b1[4];
#pragma unroll
        for (int i = 0; i < 8; ++i) a1[i] = *(const short8*)&sA[(wm * 128 + i * 16 + fr) * 64 + posk1];
#pragma unroll
        for (int j = 0; j < 4; ++j) b1[j] = *(const short8*)&sB[(wn * 64 + j * 16 + fr) * 64 + posk1];
        __builtin_amdgcn_s_setprio(1);
#pragma unroll
        for (int i = 0; i < 8; ++i)
#pragma unroll
            for (int j = 0; j < 4; ++j)
                acc[i][j] = __builtin_amdgcn_mfma_f32_16x16x32_bf16(a1[i], b1[j], acc[i][j], 0, 0, 0);
        __builtin_amdgcn_s_setprio(0);
    }

    __syncthreads();   // all reads done, no DMA outstanding; LDS reused for staging

    const int cc = lane & 15, rb4 = quad * 4;
    const bool vblk = WVT && (n0 >= 2048);

    if (!vblk) {
        // ---- epilogue: acc -> LDS bf16 [256][264] -> coalesced short8 global rows
#pragma unroll
        for (int i = 0; i < 8; ++i) {
            int row = wm * 128 + i * 16 + rb4;
#pragma unroll
            for (int j = 0; j < 4; ++j) {
                int col = wn * 64 + j * 16 + cc;
                float bv = SK ? 0.0f : bias[n0 + col];
#pragma unroll
                for (int r = 0; r < 4; ++r) {
                    float v = acc[i][j][r] + bv;
                    if (RELU) v = fmaxf(v, 0.0f);
                    SH[(row + r) * 264 + col] = f2bf(v);
                }
            }
        }
    } else {
        // ---- V epilogue: acc -> LDS TRANSPOSED Vt[col][row] (stride 264)
#pragma unroll
        for (int i = 0; i < 8; ++i) {
            int row = wm * 128 + i * 16 + rb4;
#pragma unroll
            for (int j = 0; j < 4; ++j) {
                int col = wn * 64 + j * 16 + cc;
                float bv = bias[n0 + col];
#pragma unroll
                for (int r = 0; r < 4; ++r)
                    SH[col * 264 + row + r] = f2bf(acc[i][j][r] + bv);
            }
        }
    }
    __syncthreads();

    if (!vblk) {
        short* Co = Cb + (SK ? (size_t)blockIdx.z * PSTR : 0);
#pragma unroll
        for (int it = 0; it < 16; ++it) {
            int idx = it * 512 + tid;
            int row = idx >> 5, ch = idx & 31;
            short8 v = *(const short8*)&SH[row * 264 + ch * 8];
            *(short8*)&Co[(size_t)(m0 + row) * N + n0 + ch * 8] = v;
        }
    } else {
        // vt[((b*16+h)*64+d)*1024 + tok]; whole tile lies in one b (m0 multiple of 256)
        const int bI = m0 >> 10, m0l = m0 & 1023;
#pragma unroll
        for (int it = 0; it < 16; ++it) {
            int idx = it * 512 + tid;
            int col = idx >> 5, tc = idx & 31;        // 16 cols x 32 tok-chunks per iter
            int gc  = n0 + col - 2048;
            int h   = gc >> 6, d = gc & 63;
            short8 v = *(const short8*)&SH[col * 264 + tc * 8];
            *(short8*)&VTp[((size_t)((bI * 16 + h) * 64 + d)) * 1024 + m0l + tc * 8] = v;
        }
    }
}

// ---------------------------------------------------------------- GEMM (NT) 128x128 (out-proj)
template<bool RELU, bool SK>
__global__ __launch_bounds__(256) void gemm_bt(
    const short* __restrict__ A, const short* __restrict__ Bw,
    const float* __restrict__ bias,
    short* __restrict__ Cb,
    int M, int N, int K, int Ksp)
{
    __shared__ union U {
        struct { short As[128 * 64]; short Bs[128 * 64]; } s;
        short Cs[128 * 136];
    } u;
    const int tid  = threadIdx.x;
    const int wave = tid >> 6, lane = tid & 63;
    const int m0 = blockIdx.x * 128, n0 = blockIdx.y * 128;
    const int wm = (wave & 1) * 64, wn = (wave >> 1) * 64;
    const int kbase = SK ? blockIdx.z * Ksp : 0;

    floatx4 acc[4][4];
#pragma unroll
    for (int i = 0; i < 4; ++i)
#pragma unroll
        for (int j = 0; j < 4; ++j) acc[i][j] = (floatx4){0.f, 0.f, 0.f, 0.f};

    const int srow = wave * 8 + (lane >> 3);
    const int scol = (((lane & 7) ^ ((lane >> 3) & 7))) * 8;
    const short* gA = A  + (size_t)(m0 + srow) * K + kbase + scol;
    const short* gB = Bw + (size_t)(n0 + srow) * K + kbase + scol;
    short* lA = u.s.As + wave * 512;
    short* lB = u.s.Bs + wave * 512;

    const int fr = lane & 15, quad = lane >> 4;
    const int kiters = (SK ? Ksp : K) >> 6;
    for (int kt = 0; kt < kiters; ++kt) {
#pragma unroll
        for (int s = 0; s < 4; ++s) {
            async_copy16(gA + (size_t)s * 32 * K, lA + s * 2048);
            async_copy16(gB + (size_t)s * 32 * K, lB + s * 2048);
        }
        gA += 64; gB += 64;
        __syncthreads();
#pragma unroll
        for (int ks = 0; ks < 2; ++ks) {
            short8 af[4], bf[4];
#pragma unroll
            for (int i = 0; i < 4; ++i) {
                int pos = ((ks * 4 + quad) ^ (fr & 7)) * 8;
                af[i] = *(const short8*)&u.s.As[(wm + i * 16 + fr) * 64 + pos];
                bf[i] = *(const short8*)&u.s.Bs[(wn + i * 16 + fr) * 64 + pos];
            }
#pragma unroll
            for (int i = 0; i < 4; ++i)
#pragma unroll
                for (int j = 0; j < 4; ++j)
                    acc[i][j] = __builtin_amdgcn_mfma_f32_16x16x32_bf16(af[i], bf[j], acc[i][j], 0, 0, 0);
        }
        __syncthreads();
    }

    const int cc = lane & 15;
    const int rb = (lane >> 4) * 4;
#pragma unroll
    for (int j = 0; j < 4; ++j) {
        int col = wn + j * 16 + cc;
        float bv = SK ? 0.0f : bias[n0 + col];
#pragma unroll
        for (int i = 0; i < 4; ++i) {
            int row = wm + i * 16 + rb;
#pragma unroll
            for (int r = 0; r < 4; ++r) {
                float v = acc[i][j][r] + bv;
                if (RELU) v = fmaxf(v, 0.0f);
                u.Cs[(row + r) * 136 + col] = f2bf(v);
            }
        }
    }
    __syncthreads();
    short* Co = Cb + (SK ? (size_t)blockIdx.z * PSTR : 0);
    const int trow = tid >> 4, tcol = (tid & 15) * 8;
#pragma unroll
    for (int p = 0; p < 8; ++p) {
        int row = p * 16 + trow;
        short8 vv = *(const short8*)&u.Cs[row * 136 + tcol];
        *(short8*)&Co[(size_t)(m0 + row) * N + n0 + tcol] = vv;
    }
}

// ---------------------------------------------------------------- LayerNorm
__global__ __launch_bounds__(256) void ln_kernel(
    const float* __restrict__ xa, const short* __restrict__ parts, int nparts,
    const float* __restrict__ bias,
    const float* __restrict__ g, const float* __restrict__ beta,
    float* __restrict__ outf, short* __restrict__ outb)
{
    const int row = blockIdx.x;
    const int tid = threadIdx.x;
    float4 va = ((const float4*)(xa + (size_t)row * EE))[tid];
    float4 vb = ((const float4*)bias)[tid];
    float v0 = va.x + vb.x, v1 = va.y + vb.y, v2 = va.z + vb.z, v3 = va.w + vb.w;
#pragma unroll 4
    for (int p = 0; p < nparts; ++p) {
        unsigned long long u8 = ((const unsigned long long*)(parts + p * PSTR + (size_t)row * EE))[tid];
        v0 += bf2f((short)(u8 & 0xffff));
        v1 += bf2f((short)((u8 >> 16) & 0xffff));
        v2 += bf2f((short)((u8 >> 32) & 0xffff));
        v3 += bf2f((short)(u8 >> 48));
    }
    float s  = v0 + v1 + v2 + v3;
    float ss = v0 * v0 + v1 * v1 + v2 * v2 + v3 * v3;
#pragma unroll
    for (int o = 1; o < 64; o <<= 1) { s += __shfl_xor(s, o); ss += __shfl_xor(ss, o); }
    __shared__ float red[8];
    if ((tid & 63) == 0) { red[(tid >> 6) * 2] = s; red[(tid >> 6) * 2 + 1] = ss; }
    __syncthreads();
    s  = red[0] + red[2] + red[4] + red[6];
    ss = red[1] + red[3] + red[5] + red[7];
    float mean = s * (1.0f / EE);
    float var  = ss * (1.0f / EE) - mean * mean;
    float rstd = rsqrtf(var + 1e-5f);
    float4 vg = ((const float4*)g)[tid];
    float4 vt = ((const float4*)beta)[tid];
    float o0 = (v0 - mean) * rstd * vg.x + vt.x;
    float o1 = (v1 - mean) * rstd * vg.y + vt.y;
    float o2 = (v2 - mean) * rstd * vg.z + vt.z;
    float o3 = (v3 - mean) * rstd * vg.w + vt.w;
    if (outf) ((float4*)(outf + (size_t)row * EE))[tid] = make_float4(o0, o1, o2, o3);
    if (outb) {
        unsigned long long u =
              (unsigned long long)(unsigned short)f2bf(o0)
            | ((unsigned long long)(unsigned short)f2bf(o1) << 16)
            | ((unsigned long long)(unsigned short)f2bf(o2) << 32)
            | ((unsigned long long)(unsigned short)f2bf(o3) << 48);
        ((unsigned long long*)(outb + (size_t)row * EE))[tid] = u;
    }
}

// ---------------------------------------------------------------- attention (MFMA, register softmax)
// 64-row i-tile per block (same 320-col K window serves all 64 rows since 64+2*128=320).
// Grid 1024 = 16 i-tiles x 4b x 16h (i0 slow). 512 thr / 8 waves; 3 blocks/CU
// (LDS 41KB, launch_bounds (512,6) -> VGPR cap 85, est ~76 no spill).
// K window staged ONCE into LDS (chunk-XOR swizzle, pre-swizzled global source);
// LDS reused: Kl -> Pl (P tile) -> ctx staging.
__global__ __launch_bounds__(512, 6) void attn_mfma(
    const short* __restrict__ qkv,
    const short* __restrict__ vt,
    short* __restrict__ ctxp,
    short* __restrict__ pb)     // [b][h][i][320] bf16
{
    __shared__ short Kl[64 * 320];   // 40,960 B: K stage -> P tile -> ctx tile
    __shared__ float Red[2][2][64];  //  1,024 B
    const int tid = threadIdx.x, w = tid >> 6, lane = tid & 63;
    const int quad = lane >> 4, mcol = lane & 15;
    const int id = blockIdx.x;
    const int i0 = (id >> 6) * 64, h = id & 15, b = (id >> 4) & 3;
    const int jb0 = i0 - 128;

    const short* qb = qkv + (size_t)(b * 1024) * 3072 + h * 64;
    const short* kb = qb + 1024;

    // ---- stage K window [jb0, jb0+320) x 64 into Kl (linear dest, pre-swizzled src) ----
    {
        short* dstb = Kl + w * 512;   // wave-uniform base; HW adds lane*16B
#pragma unroll
        for (int it = 0; it < 5; ++it) {
            int jo = it * 64 + w * 8 + (lane >> 3);
            int j  = min(max(jb0 + jo, 0), 1023);
            int g  = (lane & 7) ^ (jo & 7);
            async_copy16(kb + (size_t)j * 3072 + g * 8, dstb + it * 4096);
        }
    }

    // ---- Q frags (overlap with K DMA) ----
    const int mt = w >> 1, qtr = w & 1;
    const short* qrow = qb + (size_t)(i0 + mt * 16 + mcol) * 3072 + quad * 8;
    short8 aq0 = *(const short8*)qrow;
    short8 aq1 = *(const short8*)(qrow + 32);

    __syncthreads();   // drains vmcnt (K DMA + Q loads)

    // ---- QK^T from Kl ----
    floatx4 sacc[10];
#pragma unroll
    for (int c = 0; c < 10; ++c) sacc[c] = (floatx4){0.f, 0.f, 0.f, 0.f};
#pragma unroll
    for (int c = 0; c < 10; ++c) {
        int jo = qtr * 160 + c * 16 + mcol;
        const short* krow = Kl + jo * 64;
        short8 b0 = *(const short8*)&krow[((quad    ) ^ (jo & 7)) * 8];
        short8 b1 = *(const short8*)&krow[((4 + quad) ^ (jo & 7)) * 8];
        sacc[c] = __builtin_amdgcn_mfma_f32_16x16x32_bf16(aq0, b0, sacc[c], 0, 0, 0);
        sacc[c] = __builtin_amdgcn_mfma_f32_16x16x32_bf16(aq1, b1, sacc[c], 0, 0, 0);
    }

    // ---- mask+scale, half row-max (quad shuffles) ----
    const int row0 = mt * 16 + quad * 4;
#pragma unroll
    for (int r = 0; r < 4; ++r) {
        int row = row0 + r;
        float m = -1e30f;
#pragma unroll
        for (int c = 0; c < 10; ++c) {
            int jo = qtr * 160 + c * 16 + mcol;
            bool val = (jo >= row) && (jo <= row + 256) && ((unsigned)(jb0 + jo) < 1024u);
            float s = val ? sacc[c][r] * 0.125f : -1e30f;
            sacc[c][r] = s;
            m = fmaxf(m, s);
        }
        m = fmaxf(m, __shfl_xor(m, 1));
        m = fmaxf(m, __shfl_xor(m, 2));
        m = fmaxf(m, __shfl_xor(m, 4));
        m = fmaxf(m, __shfl_xor(m, 8));
        if (mcol == 0) Red[qtr][0][row] = m;
    }
    __syncthreads();
    // ---- exp + half row-sum ----
#pragma unroll
    for (int r = 0; r < 4; ++r) {
        int row = row0 + r;
        float M = fmaxf(Red[0][0][row], Red[1][0][row]);
        float l = 0.f;
#pragma unroll
        for (int c = 0; c < 10; ++c) {
            float p = __expf(sacc[c][r] - M);
            sacc[c][r] = p;
            l += p;
        }
        l += __shfl_xor(l, 1);
        l += __shfl_xor(l, 2);
        l += __shfl_xor(l, 4);
        l += __shfl_xor(l, 8);
        if (mcol == 0) Red[qtr][1][row] = l;
    }
    __syncthreads();   // all Kl reads done; safe to overwrite as Pl
    // ---- normalize, write P to swizzled LDS (aliases Kl) ----
    short* Pl = Kl;
#pragma unroll
    for (int r = 0; r < 4; ++r) {
        int row = row0 + r;
        float inv = 1.0f / (Red[0][1][row] + Red[1][1][row]);
#pragma unroll
        for (int c = 0; c < 10; ++c) {
            int jo = qtr * 160 + c * 16 + mcol;
            Pl[row * 320 + (((jo >> 3) ^ (row & 7)) * 8) + (jo & 7)] = f2bf(sacc[c][r] * inv);
        }
    }
    __syncthreads();

    // ---- PV (reads Pl + V direct from L2/L3) ----
    const int pmt = w & 3, dth = w >> 2;
    floatx4 cacc[2];
    cacc[0] = (floatx4){0.f, 0.f, 0.f, 0.f};
    cacc[1] = (floatx4){0.f, 0.f, 0.f, 0.f};
    const int prow = (pmt * 16 + mcol) * 320;
    const short* vb0 = vt + ((size_t)((b * 16 + h) * 64 + dth * 32) + mcol) * 1024;
#pragma unroll
    for (int jc = 0; jc < 10; ++jc) {
        short8 ap = *(const short8*)&Pl[prow + (((jc * 4 + quad) ^ (mcol & 7)) * 8)];
        int jg = jb0 + jc * 32 + quad * 8;
        if ((unsigned)jg >= 1024u) jg = 0;    // fully-masked frag (P=0)
        short8 bv0 = *(const short8*)(vb0 + jg);
        short8 bv1 = *(const short8*)(vb0 + (size_t)16 * 1024 + jg);
        cacc[0] = __builtin_amdgcn_mfma_f32_16x16x32_bf16(ap, bv0, cacc[0], 0, 0, 0);
        cacc[1] = __builtin_amdgcn_mfma_f32_16x16x32_bf16(ap, bv1, cacc[1], 0, 0, 0);
    }

    // ---- bulk P copy: Pl (un-swizzle) -> private pb region (contiguous) ----
    short* pbb = pb + ((size_t)((b * 16 + h) * 1024) + i0) * 320;
#pragma unroll
    for (int s = 0; s < 5; ++s) {
        int t = s * 512 + tid;
        int row = t / 40, c = t - row * 40;
        short8 v = *(const short8*)&Pl[row * 320 + ((c ^ (row & 7)) * 8)];
        *(short8*)&pbb[(size_t)t * 8] = v;     // t*8 == row*320 + c*8
    }
    __syncthreads();   // all Pl reads (PV frags + copy) complete

    // ---- ctx tile: regs -> LDS (stride 72, aliases Pl) -> coalesced rows ----
    short* Ct = Kl;
#pragma unroll
    for (int d2 = 0; d2 < 2; ++d2)
#pragma unroll
        for (int r = 0; r < 4; ++r)
            Ct[(pmt * 16 + quad * 4 + r) * 72 + dth * 32 + d2 * 16 + mcol] = f2bf(cacc[d2][r]);
    __syncthreads();
    short* cb = ctxp + (size_t)(b * 1024 + i0) * 1024 + h * 64;
    {
        int row = tid >> 3, c = tid & 7;
        short8 v = *(const short8*)&Ct[row * 72 + c * 8];
        *(short8*)&cb[(size_t)row * 1024 + c * 8] = v;
    }
}

// ---------------------------------------------------------------- head-mean reduce
__global__ __launch_bounds__(256) void pb_reduce(const short* __restrict__ pb,
                                                 float* __restrict__ aw)
{
    const int i = blockIdx.x & 1023, b = blockIdx.x >> 10;
    const int i0 = i & ~63;
    __shared__ short P[16 * 320];    // 10,240 B
    for (int t = threadIdx.x; t < 640; t += 256) {
        int hh = t / 40, c = t - hh * 40;
        ((short8*)P)[t] = *(const short8*)(pb +
            ((size_t)((b * 16 + hh) * 1024) + i) * 320 + c * 8);
    }
    __syncthreads();
    float* row = aw + ((size_t)(b * 1024) + i) * 1024;
    for (int j = threadIdx.x; j < 1024; j += 256) {
        int jo = j - i0 + 128;
        float s = 0.f;
        if ((unsigned)jo < 320u) {
#pragma unroll
            for (int hh = 0; hh < 16; ++hh)
                s += bf2f(P[hh * 320 + jo]);
            s *= (1.0f / 16.0f);
        }
        row[j] = s;
    }
}

// ---------------------------------------------------------------- launch
extern "C" void kernel_launch(void* const* d_in, const int* in_sizes, int n_in,
                              void* d_out, int out_size, void* d_ws, size_t ws_size,
                              hipStream_t stream) {
    const float* x    = (const float*)d_in[0];
    const float* wqkv = (const float*)d_in[1];
    const float* bqkv = (const float*)d_in[2];
    const float* wo   = (const float*)d_in[3];
    const float* bo   = (const float*)d_in[4];
    const float* g1   = (const float*)d_in[5];
    const float* be1  = (const float*)d_in[6];
    const float* w1   = (const float*)d_in[7];
    const float* bb1  = (const float*)d_in[8];
    const float* w2   = (const float*)d_in[9];
    const float* bb2  = (const float*)d_in[10];
    const float* g2   = (const float*)d_in[11];
    const float* be2  = (const float*)d_in[12];

    char* ws = (char*)d_ws;
    size_t off = 0;
    auto take = [&](size_t bytes) {
        void* p = ws + off;
        off += (bytes + 255) & ~(size_t)255;
        return p;
    };
    short* xb     = (short*)take((size_t)4096 * 1024 * 2);
    short* wqkv_b = (short*)take((size_t)3072 * 1024 * 2);
    short* wo_b   = (short*)take((size_t)1024 * 1024 * 2);
    short* w1_b   = (short*)take((size_t)4096 * 1024 * 2);
    short* w2_b   = (short*)take((size_t)1024 * 4096 * 2);
    short* qkv_b  = (short*)take((size_t)4096 * 3072 * 2);
    short* ctx_b  = (short*)take((size_t)4096 * 1024 * 2);
    short* ff2_p  = qkv_b;                                      // FFN2 bf16 partials x4
    short* attn_p = (short*)take((size_t)2 * 4096 * 1024 * 2);  // out-proj bf16 partials x2
    float* h_f    = (float*)take((size_t)4096 * 1024 * 4);
    short* vt_ws  = (short*)h_f;                                // vt dead before ln1 writes h_f
    short* h_b    = (short*)take((size_t)4096 * 1024 * 2);
    short* pb_ws  = (short*)take((size_t)4 * 16 * 1024 * 320 * 2);  // 41.9 MB
    short* ff_b   = pb_ws;                                      // FFN1 out aliases pb (33.6 <= 41.9)

    float* out_f = (float*)d_out;
    float* attnW = (float*)d_out + (size_t)4 * 1024 * 1024;

    // bf16 conversions (single launch)
    cvt5<<<16384, 256, 0, stream>>>(x, wqkv, wo, w1, w2, xb, wqkv_b, wo_b, w1_b, w2_b);

    // qkv projection -- 256x256 BK=64 minimal-sync; V-blocks write vt directly
    gemm256<false, false, true><<<dim3(16, 12), 512, 0, stream>>>(
        xb, wqkv_b, bqkv, qkv_b, vt_ws, 4096, 3072, 1024, 1024);

    // banded attention (MFMA, register softmax, K staged in LDS); 64-row tiles
    attn_mfma<<<1024, 512, 0, stream>>>(qkv_b, vt_ws, ctx_b, pb_ws);

    // head-mean attention weights
    pb_reduce<<<4096, 256, 0, stream>>>(pb_ws, attnW);

    // out projection, split-K=2 -> bf16 partials
    gemm_bt<false, true><<<dim3(32, 8, 2), 256, 0, stream>>>(
        ctx_b, wo_b, nullptr, attn_p, 4096, 1024, 1024, 512);

    // h = LN(x + p0 + p1 + bo)
    ln_kernel<<<4096, 256, 0, stream>>>(x, attn_p, 2, bo, g1, be1, h_f, h_b);

    // FFN1 + ReLU -> bf16 -- 256x256 BK=64 minimal-sync
    gemm256<true, false, false><<<dim3(16, 16), 512, 0, stream>>>(
        h_b, w1_b, bb1, ff_b, nullptr, 4096, 4096, 1024, 1024);

    // FFN2, split-K=4 -> bf16 partials -- 256x256 BK=64 minimal-sync
    gemm256<false, true, false><<<dim3(16, 4, 4), 512, 0, stream>>>(
        ff_b, w2_b, nullptr, ff2_p, nullptr, 4096, 1024, 4096, 1024);

    // out = LN(h + p0..p3 + bb2)
    ln_kernel<<<4096, 256, 0, stream>>>(h_f, ff2_p, 4, bb2, g2, be2, out_f, nullptr);
}

// Round 8
// 314.617 us; speedup vs baseline: 1.0607x; 1.0199x over previous
//
#include <hip/hip_runtime.h>

// Shapes fixed by setup_inputs(): B=4, L=1024, E=1024, H=16, D=64, W=128
#define BB 4
#define LL 1024
#define EE 1024
#define HH 16
#define DD 64

typedef __attribute__((ext_vector_type(8))) short short8;
typedef __attribute__((ext_vector_type(4))) float floatx4;

#define PSTR ((size_t)4096 * 1024)   // split-K partial stride (elements, bf16)

__device__ __forceinline__ float bf2f(short s) {
    union { unsigned u; float f; } c;
    c.u = ((unsigned)(unsigned short)s) << 16;
    return c.f;
}
__device__ __forceinline__ short f2bf(float f) {
    union { float f; unsigned u; } c; c.f = f;
    unsigned r = c.u + 0x7fffu + ((c.u >> 16) & 1u);
    return (short)(r >> 16);
}

__device__ __forceinline__ void async_copy16(const void* g, void* l) {
    __builtin_amdgcn_global_load_lds(
        (const __attribute__((address_space(1))) unsigned int*)g,
        (__attribute__((address_space(3))) unsigned int*)l, 16, 0, 0);
}

// ---------------------------------------------------------------- convert (all 5 tensors, one launch)
__global__ __launch_bounds__(256) void cvt5(
    const float* __restrict__ x, const float* __restrict__ wqkv,
    const float* __restrict__ wo, const float* __restrict__ w1,
    const float* __restrict__ w2,
    short* __restrict__ xb, short* __restrict__ wqkvb, short* __restrict__ wob,
    short* __restrict__ w1b, short* __restrict__ w2b)
{
    int bi = blockIdx.x;
    const float* in; short* out; int base;
    if      (bi <  4096) { in = x;    out = xb;    base = 0;     }
    else if (bi <  7168) { in = wqkv; out = wqkvb; base = 4096;  }
    else if (bi <  8192) { in = wo;   out = wob;   base = 7168;  }
    else if (bi < 12288) { in = w1;   out = w1b;   base = 8192;  }
    else                 { in = w2;   out = w2b;   base = 12288; }
    int i = (bi - base) * 256 + threadIdx.x;
    float4 v = ((const float4*)in)[i];
    unsigned long long u =
          (unsigned long long)(unsigned short)f2bf(v.x)
        | ((unsigned long long)(unsigned short)f2bf(v.y) << 16)
        | ((unsigned long long)(unsigned short)f2bf(v.z) << 32)
        | ((unsigned long long)(unsigned short)f2bf(v.w) << 48);
    ((unsigned long long*)out)[i] = u;
}

// ---------------------------------------------------------------- GEMM 256x256 (NT), BK=64 minimal-sync
// (FROZEN from R6/R7 — proven best schedule at 1 block/CU.)
// C[m,n] = sum_k A[m,k]*B[n,k] (+bias). BM=BN=256, BK=64, 512 thr / 8 waves (2Mx4N).
// LDS: 2 buffers x (A 256x64 + B 256x64 bf16) = 128 KiB.
// Chunk swizzle: 16B chunk c of row r at position c^(r&7); pre-swizzled global src,
// linear gload_lds dest; frag reads are 2-way (free), 0 conflicts measured.
// Sync: ONE __syncthreads per K-tile; stage(t+1) issued right after -> in flight
// for a full tile body (>2000 cyc >> ~900 HBM).
// WVT (qkv only): V-column blocks (n0>=2048) write acc TRANSPOSED into the C-stage
// LDS as Vt[col][row] then store coalesced rows into vt; qkv_b row-stores skipped.
template<bool RELU, bool SK, bool WVT>
__global__ __launch_bounds__(512, 2) void gemm256(
    const short* __restrict__ A, const short* __restrict__ Bw,
    const float* __restrict__ bias,
    short* __restrict__ Cb, short* __restrict__ VTp,
    int M, int N, int K, int Ksp)
{
    __shared__ short SH[67584];   // union{ 2 bufs 131072 B ; C/Vt stage 256x264x2 = 135168 B }
    const int tid  = threadIdx.x;
    const int w    = tid >> 6, lane = tid & 63;
    const int fr   = lane & 15, quad = lane >> 4;
    const int wm   = w >> 2,  wn   = w & 3;

    // XCD-bijective block swizzle (all grids have nwg % 8 == 0)
    const int gx   = gridDim.x;                 // = M-tiles
    const int flat = blockIdx.y * gx + blockIdx.x;
    const int nwg  = gx * gridDim.y;
    const int q8   = nwg >> 3;
    const int swz  = (flat & 7) * q8 + (flat >> 3);
    const int m0   = (swz % gx) * 256;
    const int n0   = (swz / gx) * 256;

    const int kb = SK ? blockIdx.z * Ksp : 0;
    const int NT = (SK ? Ksp : K) >> 6;

    const int srow = w * 8 + (lane >> 3);
    const int sg   = lane & 7;
    auto stage = [&](int s) {
        if (s >= NT) return;
#pragma unroll
        for (int i = 0; i < 4; ++i) {
            int r = i * 64 + srow;
            int g = sg ^ (r & 7);
            async_copy16(A + (size_t)(m0 + r) * K + kb + s * 64 + g * 8,
                         SH + (s & 1) * 32768 + i * 4096 + w * 512);
        }
#pragma unroll
        for (int i = 0; i < 4; ++i) {
            int r = i * 64 + srow;
            int g = sg ^ (r & 7);
            async_copy16(Bw + (size_t)(n0 + r) * K + kb + s * 64 + g * 8,
                         SH + (s & 1) * 32768 + 16384 + i * 4096 + w * 512);
        }
    };

    floatx4 acc[8][4];
#pragma unroll
    for (int i = 0; i < 8; ++i)
#pragma unroll
        for (int j = 0; j < 4; ++j) acc[i][j] = (floatx4){0.f, 0.f, 0.f, 0.f};

    stage(0);

    const int posk0 = ((quad    ) ^ (fr & 7)) * 8;
    const int posk1 = ((4 + quad) ^ (fr & 7)) * 8;

    for (int t = 0; t < NT; ++t) {
        __syncthreads();
        __builtin_amdgcn_sched_barrier(0);

        const short* sA = SH + (t & 1) * 32768;
        const short* sB = sA + 16384;

        stage(t + 1);

        short8 a0[8], b0[4];
#pragma unroll
        for (int i = 0; i < 8; ++i) a0[i] = *(const short8*)&sA[(wm * 128 + i * 16 + fr) * 64 + posk0];
#pragma unroll
        for (int j = 0; j < 4; ++j) b0[j] = *(const short8*)&sB[(wn * 64 + j * 16 + fr) * 64 + posk0];
        __builtin_amdgcn_s_setprio(1);
#pragma unroll
        for (int i = 0; i < 8; ++i)
#pragma unroll
            for (int j = 0; j < 4; ++j)
                acc[i][j] = __builtin_amdgcn_mfma_f32_16x16x32_bf16(a0[i], b0[j], acc[i][j], 0, 0, 0);
        __builtin_amdgcn_s_setprio(0);

        short8 a1[8], b1[4];
#pragma unroll
        for (int i = 0; i < 8; ++i) a1[i] = *(const short8*)&sA[(wm * 128 + i * 16 + fr) * 64 + posk1];
#pragma unroll
        for (int j = 0; j < 4; ++j) b1[j] = *(const short8*)&sB[(wn * 64 + j * 16 + fr) * 64 + posk1];
        __builtin_amdgcn_s_setprio(1);
#pragma unroll
        for (int i = 0; i < 8; ++i)
#pragma unroll
            for (int j = 0; j < 4; ++j)
                acc[i][j] = __builtin_amdgcn_mfma_f32_16x16x32_bf16(a1[i], b1[j], acc[i][j], 0, 0, 0);
        __builtin_amdgcn_s_setprio(0);
    }

    __syncthreads();

    const int cc = lane & 15, rb4 = quad * 4;
    const bool vblk = WVT && (n0 >= 2048);

    if (!vblk) {
#pragma unroll
        for (int i = 0; i < 8; ++i) {
            int row = wm * 128 + i * 16 + rb4;
#pragma unroll
            for (int j = 0; j < 4; ++j) {
                int col = wn * 64 + j * 16 + cc;
                float bv = SK ? 0.0f : bias[n0 + col];
#pragma unroll
                for (int r = 0; r < 4; ++r) {
                    float v = acc[i][j][r] + bv;
                    if (RELU) v = fmaxf(v, 0.0f);
                    SH[(row + r) * 264 + col] = f2bf(v);
                }
            }
        }
    } else {
#pragma unroll
        for (int i = 0; i < 8; ++i) {
            int row = wm * 128 + i * 16 + rb4;
#pragma unroll
            for (int j = 0; j < 4; ++j) {
                int col = wn * 64 + j * 16 + cc;
                float bv = bias[n0 + col];
#pragma unroll
                for (int r = 0; r < 4; ++r)
                    SH[col * 264 + row + r] = f2bf(acc[i][j][r] + bv);
            }
        }
    }
    __syncthreads();

    if (!vblk) {
        short* Co = Cb + (SK ? (size_t)blockIdx.z * PSTR : 0);
#pragma unroll
        for (int it = 0; it < 16; ++it) {
            int idx = it * 512 + tid;
            int row = idx >> 5, ch = idx & 31;
            short8 v = *(const short8*)&SH[row * 264 + ch * 8];
            *(short8*)&Co[(size_t)(m0 + row) * N + n0 + ch * 8] = v;
        }
    } else {
        const int bI = m0 >> 10, m0l = m0 & 1023;
#pragma unroll
        for (int it = 0; it < 16; ++it) {
            int idx = it * 512 + tid;
            int col = idx >> 5, tc = idx & 31;
            int gc  = n0 + col - 2048;
            int h   = gc >> 6, d = gc & 63;
            short8 v = *(const short8*)&SH[col * 264 + tc * 8];
            *(short8*)&VTp[((size_t)((bI * 16 + h) * 64 + d)) * 1024 + m0l + tc * 8] = v;
        }
    }
}

// ---------------------------------------------------------------- GEMM 128x128 (NT), BK=64 minimal-sync (out-proj)
// Same schedule as gemm256 at 128^2 tile: 256 thr / 4 waves (2Mx2N, 64x64/wave),
// LDS 2 bufs x (A 128x64 + B 128x64) = 64 KiB -> 2 blocks/CU (grid 512 on 256 CU);
// cross-block overlap + full-tile prefetch window. One __syncthreads per K-tile.
template<bool SK>
__global__ __launch_bounds__(256, 2) void gemm_bt2(
    const short* __restrict__ A, const short* __restrict__ Bw,
    short* __restrict__ Cb,
    int M, int N, int K, int Ksp)
{
    __shared__ short SH[32768];   // union{ 2 bufs 65536 B ; C stage 128x136x2 = 34816 B }
    const int tid  = threadIdx.x;
    const int w    = tid >> 6, lane = tid & 63;
    const int fr   = lane & 15, quad = lane >> 4;
    const int wm   = w >> 1, wn = w & 1;
    const int m0 = blockIdx.x * 128, n0 = blockIdx.y * 128;
    const int kb = SK ? blockIdx.z * Ksp : 0;
    const int NT = (SK ? Ksp : K) >> 6;

    // staging: 16 KiB per tensor per tile -> 4x16B per thread each.
    // slot = i*256 + tid -> row r = i*32 + (tid>>3), dest chunk c = tid&7,
    // source chunk g = c ^ (r&7); dest = base + i*2048 + w*512 (+ lane*16B by HW).
    const int sr8 = tid >> 3;
    const int sg  = tid & 7;
    auto stage = [&](int s) {
        if (s >= NT) return;
#pragma unroll
        for (int i = 0; i < 4; ++i) {
            int r = i * 32 + sr8;
            int g = sg ^ (r & 7);
            async_copy16(A + (size_t)(m0 + r) * K + kb + s * 64 + g * 8,
                         SH + (s & 1) * 16384 + i * 2048 + w * 512);
        }
#pragma unroll
        for (int i = 0; i < 4; ++i) {
            int r = i * 32 + sr8;
            int g = sg ^ (r & 7);
            async_copy16(Bw + (size_t)(n0 + r) * K + kb + s * 64 + g * 8,
                         SH + (s & 1) * 16384 + 8192 + i * 2048 + w * 512);
        }
    };

    floatx4 acc[4][4];
#pragma unroll
    for (int i = 0; i < 4; ++i)
#pragma unroll
        for (int j = 0; j < 4; ++j) acc[i][j] = (floatx4){0.f, 0.f, 0.f, 0.f};

    stage(0);

    const int posk0 = ((quad    ) ^ (fr & 7)) * 8;
    const int posk1 = ((4 + quad) ^ (fr & 7)) * 8;

    for (int t = 0; t < NT; ++t) {
        __syncthreads();
        __builtin_amdgcn_sched_barrier(0);

        const short* sA = SH + (t & 1) * 16384;
        const short* sB = sA + 8192;

        stage(t + 1);

        short8 a0[4], b0[4];
#pragma unroll
        for (int i = 0; i < 4; ++i) a0[i] = *(const short8*)&sA[(wm * 64 + i * 16 + fr) * 64 + posk0];
#pragma unroll
        for (int j = 0; j < 4; ++j) b0[j] = *(const short8*)&sB[(wn * 64 + j * 16 + fr) * 64 + posk0];
        __builtin_amdgcn_s_setprio(1);
#pragma unroll
        for (int i = 0; i < 4; ++i)
#pragma unroll
            for (int j = 0; j < 4; ++j)
                acc[i][j] = __builtin_amdgcn_mfma_f32_16x16x32_bf16(a0[i], b0[j], acc[i][j], 0, 0, 0);
        __builtin_amdgcn_s_setprio(0);

        short8 a1[4], b1[4];
#pragma unroll
        for (int i = 0; i < 4; ++i) a1[i] = *(const short8*)&sA[(wm * 64 + i * 16 + fr) * 64 + posk1];
#pragma unroll
        for (int j = 0; j < 4; ++j) b1[j] = *(const short8*)&sB[(wn * 64 + j * 16 + fr) * 64 + posk1];
        __builtin_amdgcn_s_setprio(1);
#pragma unroll
        for (int i = 0; i < 4; ++i)
#pragma unroll
            for (int j = 0; j < 4; ++j)
                acc[i][j] = __builtin_amdgcn_mfma_f32_16x16x32_bf16(a1[i], b1[j], acc[i][j], 0, 0, 0);
        __builtin_amdgcn_s_setprio(0);
    }

    __syncthreads();

    // epilogue: acc -> LDS bf16 [128][136] -> coalesced short8 rows
    const int cc = lane & 15, rb4 = quad * 4;
#pragma unroll
    for (int i = 0; i < 4; ++i) {
        int row = wm * 64 + i * 16 + rb4;
#pragma unroll
        for (int j = 0; j < 4; ++j) {
            int col = wn * 64 + j * 16 + cc;
#pragma unroll
            for (int r = 0; r < 4; ++r)
                SH[(row + r) * 136 + col] = f2bf(acc[i][j][r]);
        }
    }
    __syncthreads();
    short* Co = Cb + (SK ? (size_t)blockIdx.z * PSTR : 0);
    const int trow = tid >> 4, tcol = (tid & 15) * 8;
#pragma unroll
    for (int p = 0; p < 8; ++p) {
        int row = p * 16 + trow;
        short8 vv = *(const short8*)&SH[row * 136 + tcol];
        *(short8*)&Co[(size_t)(m0 + row) * N + n0 + tcol] = vv;
    }
}

// ---------------------------------------------------------------- LayerNorm
__global__ __launch_bounds__(256) void ln_kernel(
    const float* __restrict__ xa, const short* __restrict__ parts, int nparts,
    const float* __restrict__ bias,
    const float* __restrict__ g, const float* __restrict__ beta,
    float* __restrict__ outf, short* __restrict__ outb)
{
    const int row = blockIdx.x;
    const int tid = threadIdx.x;
    float4 va = ((const float4*)(xa + (size_t)row * EE))[tid];
    float4 vb = ((const float4*)bias)[tid];
    float v0 = va.x + vb.x, v1 = va.y + vb.y, v2 = va.z + vb.z, v3 = va.w + vb.w;
#pragma unroll 4
    for (int p = 0; p < nparts; ++p) {
        unsigned long long u8 = ((const unsigned long long*)(parts + p * PSTR + (size_t)row * EE))[tid];
        v0 += bf2f((short)(u8 & 0xffff));
        v1 += bf2f((short)((u8 >> 16) & 0xffff));
        v2 += bf2f((short)((u8 >> 32) & 0xffff));
        v3 += bf2f((short)(u8 >> 48));
    }
    float s  = v0 + v1 + v2 + v3;
    float ss = v0 * v0 + v1 * v1 + v2 * v2 + v3 * v3;
#pragma unroll
    for (int o = 1; o < 64; o <<= 1) { s += __shfl_xor(s, o); ss += __shfl_xor(ss, o); }
    __shared__ float red[8];
    if ((tid & 63) == 0) { red[(tid >> 6) * 2] = s; red[(tid >> 6) * 2 + 1] = ss; }
    __syncthreads();
    s  = red[0] + red[2] + red[4] + red[6];
    ss = red[1] + red[3] + red[5] + red[7];
    float mean = s * (1.0f / EE);
    float var  = ss * (1.0f / EE) - mean * mean;
    float rstd = rsqrtf(var + 1e-5f);
    float4 vg = ((const float4*)g)[tid];
    float4 vt = ((const float4*)beta)[tid];
    float o0 = (v0 - mean) * rstd * vg.x + vt.x;
    float o1 = (v1 - mean) * rstd * vg.y + vt.y;
    float o2 = (v2 - mean) * rstd * vg.z + vt.z;
    float o3 = (v3 - mean) * rstd * vg.w + vt.w;
    if (outf) ((float4*)(outf + (size_t)row * EE))[tid] = make_float4(o0, o1, o2, o3);
    if (outb) {
        unsigned long long u =
              (unsigned long long)(unsigned short)f2bf(o0)
            | ((unsigned long long)(unsigned short)f2bf(o1) << 16)
            | ((unsigned long long)(unsigned short)f2bf(o2) << 32)
            | ((unsigned long long)(unsigned short)f2bf(o3) << 48);
        ((unsigned long long*)(outb + (size_t)row * EE))[tid] = u;
    }
}

// ---------------------------------------------------------------- attention (MFMA, register softmax)
// 64-row i-tile per block (same 320-col K window serves all 64 rows since 64+2*128=320).
// Grid 1024 = 16 i-tiles x 4b x 16h (i0 slow). 512 thr / 8 waves; (512,4): no VGPR
// cap pressure (the (512,6) experiment in R7 likely spilled — reverted).
// K window staged ONCE into LDS (chunk-XOR swizzle, pre-swizzled global source);
// LDS reused: Kl -> Pl (P tile) -> ctx staging.
__global__ __launch_bounds__(512, 4) void attn_mfma(
    const short* __restrict__ qkv,
    const short* __restrict__ vt,
    short* __restrict__ ctxp,
    short* __restrict__ pb)     // [b][h][i][320] bf16
{
    __shared__ short Kl[64 * 320];   // 40,960 B: K stage -> P tile -> ctx tile
    __shared__ float Red[2][2][64];  //  1,024 B
    const int tid = threadIdx.x, w = tid >> 6, lane = tid & 63;
    const int quad = lane >> 4, mcol = lane & 15;
    const int id = blockIdx.x;
    const int i0 = (id >> 6) * 64, h = id & 15, b = (id >> 4) & 3;
    const int jb0 = i0 - 128;

    const short* qb = qkv + (size_t)(b * 1024) * 3072 + h * 64;
    const short* kb = qb + 1024;

    // ---- stage K window [jb0, jb0+320) x 64 into Kl (linear dest, pre-swizzled src) ----
    {
        short* dstb = Kl + w * 512;   // wave-uniform base; HW adds lane*16B
#pragma unroll
        for (int it = 0; it < 5; ++it) {
            int jo = it * 64 + w * 8 + (lane >> 3);
            int j  = min(max(jb0 + jo, 0), 1023);
            int g  = (lane & 7) ^ (jo & 7);
            async_copy16(kb + (size_t)j * 3072 + g * 8, dstb + it * 4096);
        }
    }

    // ---- Q frags (overlap with K DMA) ----
    const int mt = w >> 1, qtr = w & 1;
    const short* qrow = qb + (size_t)(i0 + mt * 16 + mcol) * 3072 + quad * 8;
    short8 aq0 = *(const short8*)qrow;
    short8 aq1 = *(const short8*)(qrow + 32);

    __syncthreads();   // drains vmcnt (K DMA + Q loads)

    // ---- QK^T from Kl ----
    floatx4 sacc[10];
#pragma unroll
    for (int c = 0; c < 10; ++c) sacc[c] = (floatx4){0.f, 0.f, 0.f, 0.f};
#pragma unroll
    for (int c = 0; c < 10; ++c) {
        int jo = qtr * 160 + c * 16 + mcol;
        const short* krow = Kl + jo * 64;
        short8 b0 = *(const short8*)&krow[((quad    ) ^ (jo & 7)) * 8];
        short8 b1 = *(const short8*)&krow[((4 + quad) ^ (jo & 7)) * 8];
        sacc[c] = __builtin_amdgcn_mfma_f32_16x16x32_bf16(aq0, b0, sacc[c], 0, 0, 0);
        sacc[c] = __builtin_amdgcn_mfma_f32_16x16x32_bf16(aq1, b1, sacc[c], 0, 0, 0);
    }

    // ---- mask+scale, half row-max (quad shuffles) ----
    const int row0 = mt * 16 + quad * 4;
#pragma unroll
    for (int r = 0; r < 4; ++r) {
        int row = row0 + r;
        float m = -1e30f;
#pragma unroll
        for (int c = 0; c < 10; ++c) {
            int jo = qtr * 160 + c * 16 + mcol;
            bool val = (jo >= row) && (jo <= row + 256) && ((unsigned)(jb0 + jo) < 1024u);
            float s = val ? sacc[c][r] * 0.125f : -1e30f;
            sacc[c][r] = s;
            m = fmaxf(m, s);
        }
        m = fmaxf(m, __shfl_xor(m, 1));
        m = fmaxf(m, __shfl_xor(m, 2));
        m = fmaxf(m, __shfl_xor(m, 4));
        m = fmaxf(m, __shfl_xor(m, 8));
        if (mcol == 0) Red[qtr][0][row] = m;
    }
    __syncthreads();
    // ---- exp + half row-sum ----
#pragma unroll
    for (int r = 0; r < 4; ++r) {
        int row = row0 + r;
        float M = fmaxf(Red[0][0][row], Red[1][0][row]);
        float l = 0.f;
#pragma unroll
        for (int c = 0; c < 10; ++c) {
            float p = __expf(sacc[c][r] - M);
            sacc[c][r] = p;
            l += p;
        }
        l += __shfl_xor(l, 1);
        l += __shfl_xor(l, 2);
        l += __shfl_xor(l, 4);
        l += __shfl_xor(l, 8);
        if (mcol == 0) Red[qtr][1][row] = l;
    }
    __syncthreads();   // all Kl reads done; safe to overwrite as Pl
    // ---- normalize, write P to swizzled LDS (aliases Kl) ----
    short* Pl = Kl;
#pragma unroll
    for (int r = 0; r < 4; ++r) {
        int row = row0 + r;
        float inv = 1.0f / (Red[0][1][row] + Red[1][1][row]);
#pragma unroll
        for (int c = 0; c < 10; ++c) {
            int jo = qtr * 160 + c * 16 + mcol;
            Pl[row * 320 + (((jo >> 3) ^ (row & 7)) * 8) + (jo & 7)] = f2bf(sacc[c][r] * inv);
        }
    }
    __syncthreads();

    // ---- PV (reads Pl + V direct from L2/L3) ----
    const int pmt = w & 3, dth = w >> 2;
    floatx4 cacc[2];
    cacc[0] = (floatx4){0.f, 0.f, 0.f, 0.f};
    cacc[1] = (floatx4){0.f, 0.f, 0.f, 0.f};
    const int prow = (pmt * 16 + mcol) * 320;
    const short* vb0 = vt + ((size_t)((b * 16 + h) * 64 + dth * 32) + mcol) * 1024;
#pragma unroll
    for (int jc = 0; jc < 10; ++jc) {
        short8 ap = *(const short8*)&Pl[prow + (((jc * 4 + quad) ^ (mcol & 7)) * 8)];
        int jg = jb0 + jc * 32 + quad * 8;
        if ((unsigned)jg >= 1024u) jg = 0;    // fully-masked frag (P=0)
        short8 bv0 = *(const short8*)(vb0 + jg);
        short8 bv1 = *(const short8*)(vb0 + (size_t)16 * 1024 + jg);
        cacc[0] = __builtin_amdgcn_mfma_f32_16x16x32_bf16(ap, bv0, cacc[0], 0, 0, 0);
        cacc[1] = __builtin_amdgcn_mfma_f32_16x16x32_bf16(ap, bv1, cacc[1], 0, 0, 0);
    }

    // ---- bulk P copy: Pl (un-swizzle) -> private pb region (contiguous) ----
    short* pbb = pb + ((size_t)((b * 16 + h) * 1024) + i0) * 320;
#pragma unroll
    for (int s = 0; s < 5; ++s) {
        int t = s * 512 + tid;
        int row = t / 40, c = t - row * 40;
        short8 v = *(const short8*)&Pl[row * 320 + ((c ^ (row & 7)) * 8)];
        *(short8*)&pbb[(size_t)t * 8] = v;     // t*8 == row*320 + c*8
    }
    __syncthreads();   // all Pl reads (PV frags + copy) complete

    // ---- ctx tile: regs -> LDS (stride 72, aliases Pl) -> coalesced rows ----
    short* Ct = Kl;
#pragma unroll
    for (int d2 = 0; d2 < 2; ++d2)
#pragma unroll
        for (int r = 0; r < 4; ++r)
            Ct[(pmt * 16 + quad * 4 + r) * 72 + dth * 32 + d2 * 16 + mcol] = f2bf(cacc[d2][r]);
    __syncthreads();
    short* cb = ctxp + (size_t)(b * 1024 + i0) * 1024 + h * 64;
    {
        int row = tid >> 3, c = tid & 7;
        short8 v = *(const short8*)&Ct[row * 72 + c * 8];
        *(short8*)&cb[(size_t)row * 1024 + c * 8] = v;
    }
}

// ---------------------------------------------------------------- head-mean reduce
__global__ __launch_bounds__(256) void pb_reduce(const short* __restrict__ pb,
                                                 float* __restrict__ aw)
{
    const int i = blockIdx.x & 1023, b = blockIdx.x >> 10;
    const int i0 = i & ~63;
    __shared__ short P[16 * 320];    // 10,240 B
    for (int t = threadIdx.x; t < 640; t += 256) {
        int hh = t / 40, c = t - hh * 40;
        ((short8*)P)[t] = *(const short8*)(pb +
            ((size_t)((b * 16 + hh) * 1024) + i) * 320 + c * 8);
    }
    __syncthreads();
    float* row = aw + ((size_t)(b * 1024) + i) * 1024;
    for (int j = threadIdx.x; j < 1024; j += 256) {
        int jo = j - i0 + 128;
        float s = 0.f;
        if ((unsigned)jo < 320u) {
#pragma unroll
            for (int hh = 0; hh < 16; ++hh)
                s += bf2f(P[hh * 320 + jo]);
            s *= (1.0f / 16.0f);
        }
        row[j] = s;
    }
}

// ---------------------------------------------------------------- launch
extern "C" void kernel_launch(void* const* d_in, const int* in_sizes, int n_in,
                              void* d_out, int out_size, void* d_ws, size_t ws_size,
                              hipStream_t stream) {
    const float* x    = (const float*)d_in[0];
    const float* wqkv = (const float*)d_in[1];
    const float* bqkv = (const float*)d_in[2];
    const float* wo   = (const float*)d_in[3];
    const float* bo   = (const float*)d_in[4];
    const float* g1   = (const float*)d_in[5];
    const float* be1  = (const float*)d_in[6];
    const float* w1   = (const float*)d_in[7];
    const float* bb1  = (const float*)d_in[8];
    const float* w2   = (const float*)d_in[9];
    const float* bb2  = (const float*)d_in[10];
    const float* g2   = (const float*)d_in[11];
    const float* be2  = (const float*)d_in[12];

    char* ws = (char*)d_ws;
    size_t off = 0;
    auto take = [&](size_t bytes) {
        void* p = ws + off;
        off += (bytes + 255) & ~(size_t)255;
        return p;
    };
    short* xb     = (short*)take((size_t)4096 * 1024 * 2);
    short* wqkv_b = (short*)take((size_t)3072 * 1024 * 2);
    short* wo_b   = (short*)take((size_t)1024 * 1024 * 2);
    short* w1_b   = (short*)take((size_t)4096 * 1024 * 2);
    short* w2_b   = (short*)take((size_t)1024 * 4096 * 2);
    short* qkv_b  = (short*)take((size_t)4096 * 3072 * 2);
    short* ctx_b  = (short*)take((size_t)4096 * 1024 * 2);
    short* ff2_p  = qkv_b;                                      // FFN2 bf16 partials x4
    short* attn_p = (short*)take((size_t)2 * 4096 * 1024 * 2);  // out-proj bf16 partials x2
    float* h_f    = (float*)take((size_t)4096 * 1024 * 4);
    short* vt_ws  = (short*)h_f;                                // vt dead before ln1 writes h_f
    short* h_b    = (short*)take((size_t)4096 * 1024 * 2);
    short* pb_ws  = (short*)take((size_t)4 * 16 * 1024 * 320 * 2);  // 41.9 MB
    short* ff_b   = pb_ws;                                      // FFN1 out aliases pb (33.6 <= 41.9)

    float* out_f = (float*)d_out;
    float* attnW = (float*)d_out + (size_t)4 * 1024 * 1024;

    // bf16 conversions (single launch)
    cvt5<<<16384, 256, 0, stream>>>(x, wqkv, wo, w1, w2, xb, wqkv_b, wo_b, w1_b, w2_b);

    // qkv projection -- 256x256 BK=64 minimal-sync; V-blocks write vt directly
    gemm256<false, false, true><<<dim3(16, 12), 512, 0, stream>>>(
        xb, wqkv_b, bqkv, qkv_b, vt_ws, 4096, 3072, 1024, 1024);

    // banded attention (MFMA, register softmax, K staged in LDS); 64-row tiles
    attn_mfma<<<1024, 512, 0, stream>>>(qkv_b, vt_ws, ctx_b, pb_ws);

    // head-mean attention weights
    pb_reduce<<<4096, 256, 0, stream>>>(pb_ws, attnW);

    // out projection, split-K=2 -> bf16 partials -- 128^2 minimal-sync, 2 blocks/CU
    gemm_bt2<true><<<dim3(32, 8, 2), 256, 0, stream>>>(
        ctx_b, wo_b, attn_p, 4096, 1024, 1024, 512);

    // h = LN(x + p0 + p1 + bo)
    ln_kernel<<<4096, 256, 0, stream>>>(x, attn_p, 2, bo, g1, be1, h_f, h_b);

    // FFN1 + ReLU -> bf16 -- 256x256 BK=64 minimal-sync
    gemm256<true, false, false><<<dim3(16, 16), 512, 0, stream>>>(
        h_b, w1_b, bb1, ff_b, nullptr, 4096, 4096, 1024, 1024);

    // FFN2, split-K=4 -> bf16 partials -- 256x256 BK=64 minimal-sync
    gemm256<false, true, false><<<dim3(16, 4, 4), 512, 0, stream>>>(
        ff_b, w2_b, nullptr, ff2_p, nullptr, 4096, 1024, 4096, 1024);

    // out = LN(h + p0..p3 + bb2)
    ln_kernel<<<4096, 256, 0, stream>>>(h_f, ff2_p, 4, bb2, g2, be2, out_f, nullptr);
}